// Round 4
// baseline (1255.587 us; speedup 1.0000x reference)
//
#include <hip/hip_runtime.h>

#define NN   100000
#define EE   1600000
#define HIDF 128
#define OUTF 64
#define KSEL 32
#define NB   391   // (NN + 255) >> 8 : 256-node coarse buckets

static __device__ __forceinline__ unsigned int sortable_key(float f) {
    unsigned int u = __float_as_uint(f);
    return (u & 0x80000000u) ? ~u : (u | 0x80000000u);
}

// ---------------- degree histogram ----------------
__global__ __launch_bounds__(256) void hist_kernel(const int* __restrict__ src,
                                                   const int* __restrict__ dst,
                                                   int* __restrict__ cnt_out,
                                                   int* __restrict__ cnt_in, int e) {
    int i = blockIdx.x * 256 + threadIdx.x;
    if (i < e) {
        atomicAdd(&cnt_out[src[i]], 1);
        atomicAdd(&cnt_in[dst[i]], 1);
    }
}

// ---------------- prefix scan (3 kernels) ----------------
__global__ __launch_bounds__(256) void scan_block(const int* __restrict__ cnt,
                                                  int* __restrict__ incl,
                                                  int* __restrict__ bsums, int n) {
    __shared__ int s[256];
    int t = threadIdx.x;
    int i = blockIdx.x * 256 + t;
    int v = (i < n) ? cnt[i] : 0;
    s[t] = v;
    __syncthreads();
    for (int off = 1; off < 256; off <<= 1) {
        int x = (t >= off) ? s[t - off] : 0;
        __syncthreads();
        s[t] += x;
        __syncthreads();
    }
    if (i < n) incl[i] = s[t];
    if (t == 255) bsums[blockIdx.x] = s[255];
}

__global__ __launch_bounds__(512) void scan_sums(const int* __restrict__ bsums,
                                                 int* __restrict__ boff, int nb) {
    __shared__ int s[512];
    int t = threadIdx.x;
    int v = (t < nb) ? bsums[t] : 0;
    s[t] = v;
    __syncthreads();
    for (int off = 1; off < 512; off <<= 1) {
        int x = (t >= off) ? s[t - off] : 0;
        __syncthreads();
        s[t] += x;
        __syncthreads();
    }
    boff[t] = s[t] - v;  // exclusive
}

// v5: also emits coarse-bucket bases/cursors for the binned CSR build.
// bbase[b] = row_off[b*256]; bbase[NB] = EE; bcur = working copy for bin_fill.
__global__ __launch_bounds__(256) void finalize_offsets(const int* __restrict__ incl,
                                                        const int* __restrict__ boff,
                                                        const int* __restrict__ cnt_in,
                                                        const int* __restrict__ cnt_out,
                                                        int* __restrict__ row_off,
                                                        int* __restrict__ bbase,
                                                        int* __restrict__ bcur,
                                                        float* __restrict__ dvo,
                                                        float* __restrict__ dvi, int n) {
    int i = blockIdx.x * 256 + threadIdx.x;
    if (i < n) {
        int ci = cnt_in[i];
        int val = incl[i] + boff[i >> 8];
        row_off[i + 1] = val;
        if (i == 0) {
            row_off[0] = 0;
            bbase[0] = 0;
            bcur[0] = 0;
        }
        if ((i & 255) == 255) {          // bucket boundary: row_off[(i+1)] starts bucket (i+1)>>8
            int b = (i + 1) >> 8;
            bbase[b] = val;
            bcur[b] = val;
        }
        if (i == n - 1) bbase[(n + 255) >> 8] = val;   // bbase[NB] = EE
        dvo[i] = rsqrtf((float)max(cnt_out[i], 1));
        dvi[i] = rsqrtf((float)max(ci, 1));
    }
}

// ---------------- pass A: bin edges by coarse dst-bucket ----------------
// R3 counters: csr_fill wrote 105.9MB for a 6.4MB array (16x line
// amplification from fully-random 4B scatters). Binning makes each store
// land in a dense ~33KB bucket region -> writebacks ~= data size.
__global__ __launch_bounds__(256) void bin_fill(const int* __restrict__ src,
                                                const int* __restrict__ dst,
                                                int* __restrict__ bcur,
                                                int2* __restrict__ bin, int e) {
    int i = blockIdx.x * 256 + threadIdx.x;
    if (i < e) {
        int d = dst[i];
        int pos = atomicAdd(&bcur[d >> 8], 1);
        bin[pos] = make_int2(src[i], d);
    }
}

// ---------------- pass B: bucket-local scatter with LDS cursors ----------------
// One block per 256-node bucket; per-node cursors in LDS (atomicAdd on LDS);
// stores hit the bucket's ~16KB csr slice -> L2-resident, coalesced writeback.
__global__ __launch_bounds__(256) void csr_from_bin(const int2* __restrict__ bin,
                                                    const int* __restrict__ bbase,
                                                    const int* __restrict__ row_off,
                                                    int* __restrict__ csr, int n) {
    __shared__ int cur[256];
    const int b = blockIdx.x;
    const int t = threadIdx.x;
    int node = (b << 8) + t;
    cur[t] = (node < n) ? row_off[node] : 0;
    __syncthreads();
    const int s0 = bbase[b], s1 = bbase[b + 1];
    for (int e = s0 + t; e < s1; e += 256) {
        int2 r = bin[e];
        int pos = atomicAdd(&cur[r.y & 255], 1);
        csr[pos] = r.x;
    }
}

// ---------------- GEMM [n,128] x [128,128] + bias + ReLU ----------------
// v4 structure (verified R3): 40KB LDS (As 32KB + Ws 16-row chunk 8KB, reg
// double-buffered W). launch_bounds (256,2): (256,4) caps VGPR at 64 -> spill.
__global__ __launch_bounds__(256, 2) void gemm_relu(const float* __restrict__ A,
                                                    const float* __restrict__ W,
                                                    const float* __restrict__ bias,
                                                    float* __restrict__ out, int n) {
    __shared__ float As[64][128];   // 32KB
    __shared__ float Ws[16][128];   // 8KB
    const int tid = threadIdx.x;
    const int rbase = blockIdx.x * 64;
    const int cc = tid & 31;
    const int r0 = (tid >> 5) * 8;
    float acc[8][4];
#pragma unroll
    for (int i = 0; i < 8; ++i) { acc[i][0] = 0.f; acc[i][1] = 0.f; acc[i][2] = 0.f; acc[i][3] = 0.f; }

    // prefetch W chunk 0 into regs (issued before A-stage loads)
    float4 wreg0 = *(const float4*)(W + (size_t)tid * 4);
    float4 wreg1 = *(const float4*)(W + (size_t)(tid + 256) * 4);

    // stage A (row-guarded: x is not padded)
#pragma unroll
    for (int q = 0; q < 8; ++q) {
        int f = q * 256 + tid;
        int row = rbase + (f >> 5);
        float4 v = make_float4(0.f, 0.f, 0.f, 0.f);
        if (row < n) v = *(const float4*)(A + (size_t)row * 128 + (f & 31) * 4);
        *(float4*)&As[f >> 5][(f & 31) * 4] = v;
    }

    for (int p = 0; p < 8; ++p) {
        const int kb = p * 16;
        if (p) __syncthreads();             // Ws of phase p-1 fully consumed
        *(float4*)&Ws[tid >> 5][(tid & 31) * 4] = wreg0;
        *(float4*)&Ws[(tid >> 5) + 8][(tid & 31) * 4] = wreg1;
        if (p < 7) {                        // issue next chunk early
            const float* wp = W + (size_t)(kb + 16) * 128;
            wreg0 = *(const float4*)(wp + (size_t)tid * 4);
            wreg1 = *(const float4*)(wp + (size_t)(tid + 256) * 4);
        }
        __syncthreads();
#pragma unroll
        for (int kq = 0; kq < 4; ++kq) {
            int k = kq * 4;
            float4 w0 = *(float4*)&Ws[k + 0][cc * 4];
            float4 w1 = *(float4*)&Ws[k + 1][cc * 4];
            float4 w2 = *(float4*)&Ws[k + 2][cc * 4];
            float4 w3 = *(float4*)&Ws[k + 3][cc * 4];
#pragma unroll
            for (int i = 0; i < 8; ++i) {
                float4 a = *(float4*)&As[r0 + i][kb + k];
                acc[i][0] += a.x * w0.x + a.y * w1.x + a.z * w2.x + a.w * w3.x;
                acc[i][1] += a.x * w0.y + a.y * w1.y + a.z * w2.y + a.w * w3.y;
                acc[i][2] += a.x * w0.z + a.y * w1.z + a.z * w2.z + a.w * w3.z;
                acc[i][3] += a.x * w0.w + a.y * w1.w + a.z * w2.w + a.w * w3.w;
            }
        }
    }
    float4 b4 = *(const float4*)(bias + cc * 4);
#pragma unroll
    for (int i = 0; i < 8; ++i) {
        int gr = rbase + r0 + i;
        if (gr < n) {
            float4 o = make_float4(fmaxf(acc[i][0] + b4.x, 0.f), fmaxf(acc[i][1] + b4.y, 0.f),
                                   fmaxf(acc[i][2] + b4.z, 0.f), fmaxf(acc[i][3] + b4.w, 0.f));
            *(float4*)(out + (size_t)gr * 128 + cc * 4) = o;
        }
    }
}

// ---------------- GEMM + bias + MaxK(top-32) fused in-register ----------------
// v4 structure (verified R3), launch_bounds (256,2).
__global__ __launch_bounds__(256, 2) void gemm_maxk(const float* __restrict__ A,
                                                    const float* __restrict__ W,
                                                    const float* __restrict__ bias,
                                                    const float* __restrict__ dvout,
                                                    float* __restrict__ svals, int n) {
    __shared__ float As[64][128];   // 32KB
    __shared__ float Ws[16][128];   // 8KB
    const int tid = threadIdx.x;
    const int rbase = blockIdx.x * 64;
    const int cc = tid & 31;
    const int r0 = (tid >> 5) * 8;
    float acc[8][4];
#pragma unroll
    for (int i = 0; i < 8; ++i) { acc[i][0] = 0.f; acc[i][1] = 0.f; acc[i][2] = 0.f; acc[i][3] = 0.f; }

    float4 wreg0 = *(const float4*)(W + (size_t)tid * 4);
    float4 wreg1 = *(const float4*)(W + (size_t)(tid + 256) * 4);

    // stage A (hbuf is row-padded: unguarded)
#pragma unroll
    for (int q = 0; q < 8; ++q) {
        int f = q * 256 + tid;
        *(float4*)&As[f >> 5][(f & 31) * 4] =
            *(const float4*)(A + (size_t)rbase * 128 + (size_t)f * 4);
    }

    for (int p = 0; p < 8; ++p) {
        const int kb = p * 16;
        if (p) __syncthreads();
        *(float4*)&Ws[tid >> 5][(tid & 31) * 4] = wreg0;
        *(float4*)&Ws[(tid >> 5) + 8][(tid & 31) * 4] = wreg1;
        if (p < 7) {
            const float* wp = W + (size_t)(kb + 16) * 128;
            wreg0 = *(const float4*)(wp + (size_t)tid * 4);
            wreg1 = *(const float4*)(wp + (size_t)(tid + 256) * 4);
        }
        __syncthreads();
#pragma unroll
        for (int kq = 0; kq < 4; ++kq) {
            int k = kq * 4;
            float4 w0 = *(float4*)&Ws[k + 0][cc * 4];
            float4 w1 = *(float4*)&Ws[k + 1][cc * 4];
            float4 w2 = *(float4*)&Ws[k + 2][cc * 4];
            float4 w3 = *(float4*)&Ws[k + 3][cc * 4];
#pragma unroll
            for (int i = 0; i < 8; ++i) {
                float4 a = *(float4*)&As[r0 + i][kb + k];
                acc[i][0] += a.x * w0.x + a.y * w1.x + a.z * w2.x + a.w * w3.x;
                acc[i][1] += a.x * w0.y + a.y * w1.y + a.z * w2.y + a.w * w3.y;
                acc[i][2] += a.x * w0.z + a.y * w1.z + a.z * w2.z + a.w * w3.z;
                acc[i][3] += a.x * w0.w + a.y * w1.w + a.z * w2.w + a.w * w3.w;
            }
        }
    }

    // ---- fused MaxK select (unchanged) ----
    const int lane = tid & 63;
    const int wvi = tid >> 6;
    const bool up = lane >= 32;
    const unsigned lt32 = (1u << (lane & 31)) - 1u;
    float4 b4 = *(const float4*)(bias + cc * 4);

    unsigned keys[8][4];
#pragma unroll
    for (int i = 0; i < 8; ++i) {
        acc[i][0] += b4.x; acc[i][1] += b4.y; acc[i][2] += b4.z; acc[i][3] += b4.w;
        keys[i][0] = sortable_key(acc[i][0]);
        keys[i][1] = sortable_key(acc[i][1]);
        keys[i][2] = sortable_key(acc[i][2]);
        keys[i][3] = sortable_key(acc[i][3]);
    }
    unsigned prefL[8], prefU[8];
#pragma unroll
    for (int i = 0; i < 8; ++i) { prefL[i] = 0u; prefU[i] = 0u; }

    for (int bit = 31; bit >= 8; --bit) {
        unsigned msk = 1u << bit;
#pragma unroll
        for (int i = 0; i < 8; ++i) {
            unsigned cL = prefL[i] | msk;
            unsigned cU = prefU[i] | msk;
            unsigned myc = up ? cU : cL;
            unsigned long long b0 = __ballot(keys[i][0] >= myc);
            unsigned long long b1 = __ballot(keys[i][1] >= myc);
            unsigned long long b2 = __ballot(keys[i][2] >= myc);
            unsigned long long b3 = __ballot(keys[i][3] >= myc);
            int cntL = __popc((unsigned)b0) + __popc((unsigned)b1) +
                       __popc((unsigned)b2) + __popc((unsigned)b3);
            int cntU = __popc((unsigned)(b0 >> 32)) + __popc((unsigned)(b1 >> 32)) +
                       __popc((unsigned)(b2 >> 32)) + __popc((unsigned)(b3 >> 32));
            prefL[i] = (cntL >= KSEL) ? cL : prefL[i];
            prefU[i] = (cntU >= KSEL) ? cU : prefU[i];
        }
    }

#pragma unroll 1
    for (int i = 0; i < 8; ++i) {
        int row = rbase + 16 * wvi + i + (up ? 8 : 0);
        unsigned myp = up ? prefU[i] : prefL[i];
        unsigned kb0 = keys[i][0] & 0xFFFFFF00u, kb1 = keys[i][1] & 0xFFFFFF00u;
        unsigned kb2 = keys[i][2] & 0xFFFFFF00u, kb3 = keys[i][3] & 0xFFFFFF00u;
        unsigned long long g0 = __ballot(kb0 > myp), g1 = __ballot(kb1 > myp);
        unsigned long long g2 = __ballot(kb2 > myp), g3 = __ballot(kb3 > myp);
        unsigned long long e0 = __ballot(kb0 == myp), e1 = __ballot(kb1 == myp);
        unsigned long long e2 = __ballot(kb2 == myp), e3 = __ballot(kb3 == myp);
        unsigned gh0 = up ? (unsigned)(g0 >> 32) : (unsigned)g0;
        unsigned gh1 = up ? (unsigned)(g1 >> 32) : (unsigned)g1;
        unsigned gh2 = up ? (unsigned)(g2 >> 32) : (unsigned)g2;
        unsigned gh3 = up ? (unsigned)(g3 >> 32) : (unsigned)g3;
        unsigned eh0 = up ? (unsigned)(e0 >> 32) : (unsigned)e0;
        unsigned eh1 = up ? (unsigned)(e1 >> 32) : (unsigned)e1;
        unsigned eh2 = up ? (unsigned)(e2 >> 32) : (unsigned)e2;
        unsigned eh3 = up ? (unsigned)(e3 >> 32) : (unsigned)e3;
        int m = __popc(gh0) + __popc(gh1) + __popc(gh2) + __popc(gh3);
        int need = KSEL - m;
        int gpos = __popc(gh0 & lt32) + __popc(gh1 & lt32) + __popc(gh2 & lt32) + __popc(gh3 & lt32);
        int epos = __popc(eh0 & lt32) + __popc(eh1 & lt32) + __popc(eh2 & lt32) + __popc(eh3 & lt32);
        bool ok = row < n;
        float ds = dvout[row];
        size_t base = (size_t)row * 32;
        unsigned cbit = (unsigned)(lane & 31);
        // j = 0
        {
            int slot = -1;
            if (kb0 > myp) slot = gpos;
            else if (kb0 == myp && epos < need) slot = m + epos;
            if (slot >= 0 && ok) {
                unsigned u = (__float_as_uint(acc[i][0] * ds) & 0xFFFFFF80u) | (unsigned)(cc * 4 + 0);
                svals[base + slot] = __uint_as_float(u);
            }
            gpos += (gh0 >> cbit) & 1u;
            epos += (eh0 >> cbit) & 1u;
        }
        // j = 1
        {
            int slot = -1;
            if (kb1 > myp) slot = gpos;
            else if (kb1 == myp && epos < need) slot = m + epos;
            if (slot >= 0 && ok) {
                unsigned u = (__float_as_uint(acc[i][1] * ds) & 0xFFFFFF80u) | (unsigned)(cc * 4 + 1);
                svals[base + slot] = __uint_as_float(u);
            }
            gpos += (gh1 >> cbit) & 1u;
            epos += (eh1 >> cbit) & 1u;
        }
        // j = 2
        {
            int slot = -1;
            if (kb2 > myp) slot = gpos;
            else if (kb2 == myp && epos < need) slot = m + epos;
            if (slot >= 0 && ok) {
                unsigned u = (__float_as_uint(acc[i][2] * ds) & 0xFFFFFF80u) | (unsigned)(cc * 4 + 2);
                svals[base + slot] = __uint_as_float(u);
            }
            gpos += (gh2 >> cbit) & 1u;
            epos += (eh2 >> cbit) & 1u;
        }
        // j = 3
        {
            int slot = -1;
            if (kb3 > myp) slot = gpos;
            else if (kb3 == myp && epos < need) slot = m + epos;
            if (slot >= 0 && ok) {
                unsigned u = (__float_as_uint(acc[i][3] * ds) & 0xFFFFFF80u) | (unsigned)(cc * 4 + 3);
                svals[base + slot] = __uint_as_float(u);
            }
        }
    }
}

// ---------------- CSR aggregation: atomic-free ----------------
__global__ __launch_bounds__(256) void agg_kernel(const float* __restrict__ svals,
                                                  const int* __restrict__ row_off,
                                                  const int* __restrict__ csr_src,
                                                  const float* __restrict__ dvin,
                                                  const float* __restrict__ bg,
                                                  float* __restrict__ out, int n) {
    __shared__ float acc[4][2][128];  // [wave][slot][feature], wave-private
    const int wv = threadIdx.x >> 6;
    const int lane = threadIdx.x & 63;
    const int sub = lane >> 5;   // which edge slot
    const int j = lane & 31;     // entry within record
    const int node = blockIdx.x * 4 + wv;
    float* base0 = &acc[wv][0][0];
    base0[lane] = 0.f;
    base0[lane + 64] = 0.f;
    base0[lane + 128] = 0.f;
    base0[lane + 192] = 0.f;
    if (node < n) {
        int s0 = row_off[node], s1 = row_off[node + 1];
        float* Ac = &acc[wv][sub][0];
        int e = s0 + sub;
        for (; e + 2 < s1; e += 4) {
            int sA = csr_src[e];
            int sB = csr_src[e + 2];
            float vA = svals[(size_t)sA * 32 + j];
            float vB = svals[(size_t)sB * 32 + j];
            int fA = (int)(__float_as_uint(vA) & 127u);
            Ac[fA] += vA;
            int fB = (int)(__float_as_uint(vB) & 127u);
            Ac[fB] += vB;
        }
        for (; e < s1; e += 2) {
            int sA = csr_src[e];
            float vA = svals[(size_t)sA * 32 + j];
            int fA = (int)(__float_as_uint(vA) & 127u);
            Ac[fA] += vA;
        }
    }
    if (node < n) {
        float dv = dvin[node];
        float r0 = acc[wv][0][lane] + acc[wv][1][lane];
        float r1 = acc[wv][0][lane + 64] + acc[wv][1][lane + 64];
        out[(size_t)node * 128 + lane] = r0 * dv + bg[lane];
        out[(size_t)node * 128 + lane + 64] = r1 * dv + bg[lane + 64];
    }
}

// ---------------- GEMM [n,128] x [128,64] + bias -> d_out ----------------
// v4 (verified R3): 40KB LDS, (256,2), A index [kb + k].
__global__ __launch_bounds__(256, 2) void gemm_out64(const float* __restrict__ A,
                                                     const float* __restrict__ W,
                                                     const float* __restrict__ bias,
                                                     float* __restrict__ out, int n) {
    __shared__ float As[64][128];   // 32KB
    __shared__ float Ws[32][64];    // 8KB
    const int tid = threadIdx.x;
    const int rbase = blockIdx.x * 64;
    const int cc = tid & 15;
    const int r0 = (tid >> 4) * 4;
    float acc[4][4];
#pragma unroll
    for (int i = 0; i < 4; ++i) { acc[i][0] = 0.f; acc[i][1] = 0.f; acc[i][2] = 0.f; acc[i][3] = 0.f; }

    float4 wreg0 = *(const float4*)(W + (size_t)tid * 4);
    float4 wreg1 = *(const float4*)(W + (size_t)(tid + 256) * 4);

#pragma unroll
    for (int q = 0; q < 8; ++q) {
        int f = q * 256 + tid;
        *(float4*)&As[f >> 5][(f & 31) * 4] =
            *(const float4*)(A + (size_t)rbase * 128 + (size_t)f * 4);   // hbuf padded
    }

    for (int p = 0; p < 4; ++p) {
        const int kb = p * 32;
        if (p) __syncthreads();
        *(float4*)&Ws[tid >> 4][(tid & 15) * 4] = wreg0;
        *(float4*)&Ws[(tid >> 4) + 16][(tid & 15) * 4] = wreg1;
        if (p < 3) {
            const float* wp = W + (size_t)(kb + 32) * 64;
            wreg0 = *(const float4*)(wp + (size_t)tid * 4);
            wreg1 = *(const float4*)(wp + (size_t)(tid + 256) * 4);
        }
        __syncthreads();
#pragma unroll
        for (int kq = 0; kq < 8; ++kq) {
            int k = kq * 4;
            float4 w0 = *(float4*)&Ws[k + 0][cc * 4];
            float4 w1 = *(float4*)&Ws[k + 1][cc * 4];
            float4 w2 = *(float4*)&Ws[k + 2][cc * 4];
            float4 w3 = *(float4*)&Ws[k + 3][cc * 4];
#pragma unroll
            for (int i = 0; i < 4; ++i) {
                float4 a = *(float4*)&As[r0 + i][kb + k];
                acc[i][0] += a.x * w0.x + a.y * w1.x + a.z * w2.x + a.w * w3.x;
                acc[i][1] += a.x * w0.y + a.y * w1.y + a.z * w2.y + a.w * w3.y;
                acc[i][2] += a.x * w0.z + a.y * w1.z + a.z * w2.z + a.w * w3.z;
                acc[i][3] += a.x * w0.w + a.y * w1.w + a.z * w2.w + a.w * w3.w;
            }
        }
    }
    float4 b4 = *(const float4*)(bias + cc * 4);
#pragma unroll
    for (int i = 0; i < 4; ++i) {
        int gr = rbase + r0 + i;
        if (gr < n) {
            float4 o = make_float4(acc[i][0] + b4.x, acc[i][1] + b4.y,
                                   acc[i][2] + b4.z, acc[i][3] + b4.w);
            *(float4*)(out + (size_t)gr * 64 + cc * 4) = o;
        }
    }
}

extern "C" void kernel_launch(void* const* d_in, const int* in_sizes, int n_in,
                              void* d_out, int out_size, void* d_ws, size_t ws_size,
                              hipStream_t stream) {
    const float* x     = (const float*)d_in[0];
    const int*   src   = (const int*)d_in[1];
    const int*   dst   = (const int*)d_in[2];
    const float* W_in  = (const float*)d_in[3];
    const float* b_in  = (const float*)d_in[4];
    const float* W1    = (const float*)d_in[5];
    const float* b1    = (const float*)d_in[6];
    const float* bg1   = (const float*)d_in[7];
    const float* W2    = (const float*)d_in[8];
    const float* b2    = (const float*)d_in[9];
    const float* bg2   = (const float*)d_in[10];
    const float* W_out = (const float*)d_in[11];
    const float* b_out = (const float*)d_in[12];
    float* out = (float*)d_out;

    char* p = (char*)d_ws;
    auto carve = [&](size_t bytes) {
        char* r = p;
        p += (bytes + 255) & ~(size_t)255;
        return r;
    };
    int*   cnt_out = (int*)carve((size_t)NN * 4);
    int*   cnt_in  = (int*)carve((size_t)NN * 4);
    float* dvout   = (float*)carve((size_t)(NN + 128) * 4);  // padded: gemm_maxk reads OOB rows
    float* dvin    = (float*)carve((size_t)NN * 4);
    int*   incl    = (int*)carve((size_t)NN * 4);
    int*   bsums   = (int*)carve(512 * 4);
    int*   boff    = (int*)carve(512 * 4);
    int*   row_off = (int*)carve((size_t)(NN + 1) * 4);
    int*   bbase   = (int*)carve((size_t)(NB + 1) * 4);
    int*   bcur    = (int*)carve((size_t)(NB + 1) * 4);
    int*   csr_src = (int*)carve((size_t)EE * 4);
    float* hbuf    = (float*)carve((size_t)(NN + 128) * HIDF * 4);  // padded rows
    float* svals   = (float*)carve((size_t)NN * KSEL * 4);

    // bin[] (12.8MB) aliases hbuf (51MB): bin is consumed by csr_from_bin
    // before gemm_relu first writes hbuf (same-stream ordering).
    int2* bin = (int2*)hbuf;

    const int gN   = (NN + 255) / 256;   // 391
    const int gE   = (EE + 255) / 256;   // 6250
    const int gT   = (NN + 63) / 64;     // 1563 row tiles
    const int gAgg = (NN + 3) / 4;       // 25000

    hipMemsetAsync(cnt_out, 0, (size_t)NN * 4, stream);
    hipMemsetAsync(cnt_in, 0, (size_t)NN * 4, stream);
    hist_kernel<<<gE, 256, 0, stream>>>(src, dst, cnt_out, cnt_in, EE);
    scan_block<<<gN, 256, 0, stream>>>(cnt_in, incl, bsums, NN);
    scan_sums<<<1, 512, 0, stream>>>(bsums, boff, gN);
    finalize_offsets<<<gN, 256, 0, stream>>>(incl, boff, cnt_in, cnt_out, row_off,
                                             bbase, bcur, dvout, dvin, NN);
    bin_fill<<<gE, 256, 0, stream>>>(src, dst, bcur, bin, EE);
    csr_from_bin<<<NB, 256, 0, stream>>>(bin, bbase, row_off, csr_src, NN);

    gemm_relu<<<gT, 256, 0, stream>>>(x, W_in, b_in, hbuf, NN);

    gemm_maxk<<<gT, 256, 0, stream>>>(hbuf, W1, b1, dvout, svals, NN);
    agg_kernel<<<gAgg, 256, 0, stream>>>(svals, row_off, csr_src, dvin, bg1, hbuf, NN);

    gemm_maxk<<<gT, 256, 0, stream>>>(hbuf, W2, b2, dvout, svals, NN);
    agg_kernel<<<gAgg, 256, 0, stream>>>(svals, row_off, csr_src, dvin, bg2, hbuf, NN);

    gemm_out64<<<gT, 256, 0, stream>>>(hbuf, W_out, b_out, out, NN);
}

// Round 5
// 773.794 us; speedup vs baseline: 1.6226x; 1.6226x over previous
//
#include <hip/hip_runtime.h>

#define NN   100000
#define EE   1600000
#define HIDF 128
#define OUTF 64
#define KSEL 32
#define BSH  3                   // log2(nodes per bucket)
#define NBK  ((NN + 7) >> BSH)   // 12500 8-node buckets

static __device__ __forceinline__ unsigned int sortable_key(float f) {
    unsigned int u = __float_as_uint(f);
    return (u & 0x80000000u) ? ~u : (u | 0x80000000u);
}

// ---------------- degree histogram ----------------
__global__ __launch_bounds__(256) void hist_kernel(const int* __restrict__ src,
                                                   const int* __restrict__ dst,
                                                   int* __restrict__ cnt_out,
                                                   int* __restrict__ cnt_in, int e) {
    int i = blockIdx.x * 256 + threadIdx.x;
    if (i < e) {
        atomicAdd(&cnt_out[src[i]], 1);
        atomicAdd(&cnt_in[dst[i]], 1);
    }
}

// ---------------- prefix scan (3 kernels) ----------------
__global__ __launch_bounds__(256) void scan_block(const int* __restrict__ cnt,
                                                  int* __restrict__ incl,
                                                  int* __restrict__ bsums, int n) {
    __shared__ int s[256];
    int t = threadIdx.x;
    int i = blockIdx.x * 256 + t;
    int v = (i < n) ? cnt[i] : 0;
    s[t] = v;
    __syncthreads();
    for (int off = 1; off < 256; off <<= 1) {
        int x = (t >= off) ? s[t - off] : 0;
        __syncthreads();
        s[t] += x;
        __syncthreads();
    }
    if (i < n) incl[i] = s[t];
    if (t == 255) bsums[blockIdx.x] = s[255];
}

__global__ __launch_bounds__(512) void scan_sums(const int* __restrict__ bsums,
                                                 int* __restrict__ boff, int nb) {
    __shared__ int s[512];
    int t = threadIdx.x;
    int v = (t < nb) ? bsums[t] : 0;
    s[t] = v;
    __syncthreads();
    for (int off = 1; off < 512; off <<= 1) {
        int x = (t >= off) ? s[t - off] : 0;
        __syncthreads();
        s[t] += x;
        __syncthreads();
    }
    boff[t] = s[t] - v;  // exclusive
}

// v6: emits 8-node-bucket bases/cursors. R4 model: same-address atomic RMW
// ~136ns; time = (edges/buckets) * 136ns. 391 buckets -> 558us measured;
// 12500 buckets -> ~17us predicted.
__global__ __launch_bounds__(256) void finalize_offsets(const int* __restrict__ incl,
                                                        const int* __restrict__ boff,
                                                        const int* __restrict__ cnt_in,
                                                        const int* __restrict__ cnt_out,
                                                        int* __restrict__ row_off,
                                                        int* __restrict__ bbase,
                                                        int* __restrict__ bcur,
                                                        float* __restrict__ dvo,
                                                        float* __restrict__ dvi, int n) {
    int i = blockIdx.x * 256 + threadIdx.x;
    if (i < n) {
        int ci = cnt_in[i];
        int val = incl[i] + boff[i >> 8];
        row_off[i + 1] = val;
        if (i == 0) {
            row_off[0] = 0;
            bbase[0] = 0;
            bcur[0] = 0;
        }
        if ((i & ((1 << BSH) - 1)) == ((1 << BSH) - 1)) {  // bucket boundary
            int b = (i + 1) >> BSH;
            bbase[b] = val;
            bcur[b] = val;
        }
        dvo[i] = rsqrtf((float)max(cnt_out[i], 1));
        dvi[i] = rsqrtf((float)max(ci, 1));
    }
}

// ---------------- pass A: bin edges by 8-node dst-bucket ----------------
__global__ __launch_bounds__(256) void bin_fill(const int* __restrict__ src,
                                                const int* __restrict__ dst,
                                                int* __restrict__ bcur,
                                                int2* __restrict__ bin, int e) {
    int i = blockIdx.x * 256 + threadIdx.x;
    if (i < e) {
        int d = dst[i];
        int pos = atomicAdd(&bcur[d >> BSH], 1);
        bin[pos] = make_int2(src[i], d);
    }
}

// ---------------- pass B: bucket-local scatter with LDS cursors ----------------
// One 128-thread block per 8-node bucket (avg 128 edges); stores hit the
// bucket's ~512B csr slice -> L2-resident, dense writeback.
__global__ __launch_bounds__(128) void csr_from_bin(const int2* __restrict__ bin,
                                                    const int* __restrict__ bbase,
                                                    const int* __restrict__ row_off,
                                                    int* __restrict__ csr, int n) {
    __shared__ int cur[1 << BSH];
    const int b = blockIdx.x;
    const int t = threadIdx.x;
    if (t < (1 << BSH)) {
        int node = (b << BSH) + t;
        cur[t] = (node < n) ? row_off[node] : 0;
    }
    __syncthreads();
    const int s0 = bbase[b], s1 = bbase[b + 1];
    for (int e = s0 + t; e < s1; e += 128) {
        int2 r = bin[e];
        int pos = atomicAdd(&cur[r.y & ((1 << BSH) - 1)], 1);
        csr[pos] = r.x;
    }
}

// ---------------- GEMM [n,128] x [128,128] + bias + ReLU ----------------
// v4 structure (verified R3): 40KB LDS (As 32KB + Ws 16-row chunk 8KB, reg
// double-buffered W). launch_bounds (256,2): (256,4) caps VGPR at 64 -> spill.
__global__ __launch_bounds__(256, 2) void gemm_relu(const float* __restrict__ A,
                                                    const float* __restrict__ W,
                                                    const float* __restrict__ bias,
                                                    float* __restrict__ out, int n) {
    __shared__ float As[64][128];   // 32KB
    __shared__ float Ws[16][128];   // 8KB
    const int tid = threadIdx.x;
    const int rbase = blockIdx.x * 64;
    const int cc = tid & 31;
    const int r0 = (tid >> 5) * 8;
    float acc[8][4];
#pragma unroll
    for (int i = 0; i < 8; ++i) { acc[i][0] = 0.f; acc[i][1] = 0.f; acc[i][2] = 0.f; acc[i][3] = 0.f; }

    // prefetch W chunk 0 into regs (issued before A-stage loads)
    float4 wreg0 = *(const float4*)(W + (size_t)tid * 4);
    float4 wreg1 = *(const float4*)(W + (size_t)(tid + 256) * 4);

    // stage A (row-guarded: x is not padded)
#pragma unroll
    for (int q = 0; q < 8; ++q) {
        int f = q * 256 + tid;
        int row = rbase + (f >> 5);
        float4 v = make_float4(0.f, 0.f, 0.f, 0.f);
        if (row < n) v = *(const float4*)(A + (size_t)row * 128 + (f & 31) * 4);
        *(float4*)&As[f >> 5][(f & 31) * 4] = v;
    }

    for (int p = 0; p < 8; ++p) {
        const int kb = p * 16;
        if (p) __syncthreads();             // Ws of phase p-1 fully consumed
        *(float4*)&Ws[tid >> 5][(tid & 31) * 4] = wreg0;
        *(float4*)&Ws[(tid >> 5) + 8][(tid & 31) * 4] = wreg1;
        if (p < 7) {                        // issue next chunk early
            const float* wp = W + (size_t)(kb + 16) * 128;
            wreg0 = *(const float4*)(wp + (size_t)tid * 4);
            wreg1 = *(const float4*)(wp + (size_t)(tid + 256) * 4);
        }
        __syncthreads();
#pragma unroll
        for (int kq = 0; kq < 4; ++kq) {
            int k = kq * 4;
            float4 w0 = *(float4*)&Ws[k + 0][cc * 4];
            float4 w1 = *(float4*)&Ws[k + 1][cc * 4];
            float4 w2 = *(float4*)&Ws[k + 2][cc * 4];
            float4 w3 = *(float4*)&Ws[k + 3][cc * 4];
#pragma unroll
            for (int i = 0; i < 8; ++i) {
                float4 a = *(float4*)&As[r0 + i][kb + k];
                acc[i][0] += a.x * w0.x + a.y * w1.x + a.z * w2.x + a.w * w3.x;
                acc[i][1] += a.x * w0.y + a.y * w1.y + a.z * w2.y + a.w * w3.y;
                acc[i][2] += a.x * w0.z + a.y * w1.z + a.z * w2.z + a.w * w3.z;
                acc[i][3] += a.x * w0.w + a.y * w1.w + a.z * w2.w + a.w * w3.w;
            }
        }
    }
    float4 b4 = *(const float4*)(bias + cc * 4);
#pragma unroll
    for (int i = 0; i < 8; ++i) {
        int gr = rbase + r0 + i;
        if (gr < n) {
            float4 o = make_float4(fmaxf(acc[i][0] + b4.x, 0.f), fmaxf(acc[i][1] + b4.y, 0.f),
                                   fmaxf(acc[i][2] + b4.z, 0.f), fmaxf(acc[i][3] + b4.w, 0.f));
            *(float4*)(out + (size_t)gr * 128 + cc * 4) = o;
        }
    }
}

// ---------------- GEMM + bias + MaxK(top-32) fused in-register ----------------
// v4 structure (verified R3), launch_bounds (256,2).
__global__ __launch_bounds__(256, 2) void gemm_maxk(const float* __restrict__ A,
                                                    const float* __restrict__ W,
                                                    const float* __restrict__ bias,
                                                    const float* __restrict__ dvout,
                                                    float* __restrict__ svals, int n) {
    __shared__ float As[64][128];   // 32KB
    __shared__ float Ws[16][128];   // 8KB
    const int tid = threadIdx.x;
    const int rbase = blockIdx.x * 64;
    const int cc = tid & 31;
    const int r0 = (tid >> 5) * 8;
    float acc[8][4];
#pragma unroll
    for (int i = 0; i < 8; ++i) { acc[i][0] = 0.f; acc[i][1] = 0.f; acc[i][2] = 0.f; acc[i][3] = 0.f; }

    float4 wreg0 = *(const float4*)(W + (size_t)tid * 4);
    float4 wreg1 = *(const float4*)(W + (size_t)(tid + 256) * 4);

    // stage A (hbuf is row-padded: unguarded)
#pragma unroll
    for (int q = 0; q < 8; ++q) {
        int f = q * 256 + tid;
        *(float4*)&As[f >> 5][(f & 31) * 4] =
            *(const float4*)(A + (size_t)rbase * 128 + (size_t)f * 4);
    }

    for (int p = 0; p < 8; ++p) {
        const int kb = p * 16;
        if (p) __syncthreads();
        *(float4*)&Ws[tid >> 5][(tid & 31) * 4] = wreg0;
        *(float4*)&Ws[(tid >> 5) + 8][(tid & 31) * 4] = wreg1;
        if (p < 7) {
            const float* wp = W + (size_t)(kb + 16) * 128;
            wreg0 = *(const float4*)(wp + (size_t)tid * 4);
            wreg1 = *(const float4*)(wp + (size_t)(tid + 256) * 4);
        }
        __syncthreads();
#pragma unroll
        for (int kq = 0; kq < 4; ++kq) {
            int k = kq * 4;
            float4 w0 = *(float4*)&Ws[k + 0][cc * 4];
            float4 w1 = *(float4*)&Ws[k + 1][cc * 4];
            float4 w2 = *(float4*)&Ws[k + 2][cc * 4];
            float4 w3 = *(float4*)&Ws[k + 3][cc * 4];
#pragma unroll
            for (int i = 0; i < 8; ++i) {
                float4 a = *(float4*)&As[r0 + i][kb + k];
                acc[i][0] += a.x * w0.x + a.y * w1.x + a.z * w2.x + a.w * w3.x;
                acc[i][1] += a.x * w0.y + a.y * w1.y + a.z * w2.y + a.w * w3.y;
                acc[i][2] += a.x * w0.z + a.y * w1.z + a.z * w2.z + a.w * w3.z;
                acc[i][3] += a.x * w0.w + a.y * w1.w + a.z * w2.w + a.w * w3.w;
            }
        }
    }

    // ---- fused MaxK select (unchanged) ----
    const int lane = tid & 63;
    const int wvi = tid >> 6;
    const bool up = lane >= 32;
    const unsigned lt32 = (1u << (lane & 31)) - 1u;
    float4 b4 = *(const float4*)(bias + cc * 4);

    unsigned keys[8][4];
#pragma unroll
    for (int i = 0; i < 8; ++i) {
        acc[i][0] += b4.x; acc[i][1] += b4.y; acc[i][2] += b4.z; acc[i][3] += b4.w;
        keys[i][0] = sortable_key(acc[i][0]);
        keys[i][1] = sortable_key(acc[i][1]);
        keys[i][2] = sortable_key(acc[i][2]);
        keys[i][3] = sortable_key(acc[i][3]);
    }
    unsigned prefL[8], prefU[8];
#pragma unroll
    for (int i = 0; i < 8; ++i) { prefL[i] = 0u; prefU[i] = 0u; }

    for (int bit = 31; bit >= 8; --bit) {
        unsigned msk = 1u << bit;
#pragma unroll
        for (int i = 0; i < 8; ++i) {
            unsigned cL = prefL[i] | msk;
            unsigned cU = prefU[i] | msk;
            unsigned myc = up ? cU : cL;
            unsigned long long b0 = __ballot(keys[i][0] >= myc);
            unsigned long long b1 = __ballot(keys[i][1] >= myc);
            unsigned long long b2 = __ballot(keys[i][2] >= myc);
            unsigned long long b3 = __ballot(keys[i][3] >= myc);
            int cntL = __popc((unsigned)b0) + __popc((unsigned)b1) +
                       __popc((unsigned)b2) + __popc((unsigned)b3);
            int cntU = __popc((unsigned)(b0 >> 32)) + __popc((unsigned)(b1 >> 32)) +
                       __popc((unsigned)(b2 >> 32)) + __popc((unsigned)(b3 >> 32));
            prefL[i] = (cntL >= KSEL) ? cL : prefL[i];
            prefU[i] = (cntU >= KSEL) ? cU : prefU[i];
        }
    }

#pragma unroll 1
    for (int i = 0; i < 8; ++i) {
        int row = rbase + 16 * wvi + i + (up ? 8 : 0);
        unsigned myp = up ? prefU[i] : prefL[i];
        unsigned kb0 = keys[i][0] & 0xFFFFFF00u, kb1 = keys[i][1] & 0xFFFFFF00u;
        unsigned kb2 = keys[i][2] & 0xFFFFFF00u, kb3 = keys[i][3] & 0xFFFFFF00u;
        unsigned long long g0 = __ballot(kb0 > myp), g1 = __ballot(kb1 > myp);
        unsigned long long g2 = __ballot(kb2 > myp), g3 = __ballot(kb3 > myp);
        unsigned long long e0 = __ballot(kb0 == myp), e1 = __ballot(kb1 == myp);
        unsigned long long e2 = __ballot(kb2 == myp), e3 = __ballot(kb3 == myp);
        unsigned gh0 = up ? (unsigned)(g0 >> 32) : (unsigned)g0;
        unsigned gh1 = up ? (unsigned)(g1 >> 32) : (unsigned)g1;
        unsigned gh2 = up ? (unsigned)(g2 >> 32) : (unsigned)g2;
        unsigned gh3 = up ? (unsigned)(g3 >> 32) : (unsigned)g3;
        unsigned eh0 = up ? (unsigned)(e0 >> 32) : (unsigned)e0;
        unsigned eh1 = up ? (unsigned)(e1 >> 32) : (unsigned)e1;
        unsigned eh2 = up ? (unsigned)(e2 >> 32) : (unsigned)e2;
        unsigned eh3 = up ? (unsigned)(e3 >> 32) : (unsigned)e3;
        int m = __popc(gh0) + __popc(gh1) + __popc(gh2) + __popc(gh3);
        int need = KSEL - m;
        int gpos = __popc(gh0 & lt32) + __popc(gh1 & lt32) + __popc(gh2 & lt32) + __popc(gh3 & lt32);
        int epos = __popc(eh0 & lt32) + __popc(eh1 & lt32) + __popc(eh2 & lt32) + __popc(eh3 & lt32);
        bool ok = row < n;
        float ds = dvout[row];
        size_t base = (size_t)row * 32;
        unsigned cbit = (unsigned)(lane & 31);
        // j = 0
        {
            int slot = -1;
            if (kb0 > myp) slot = gpos;
            else if (kb0 == myp && epos < need) slot = m + epos;
            if (slot >= 0 && ok) {
                unsigned u = (__float_as_uint(acc[i][0] * ds) & 0xFFFFFF80u) | (unsigned)(cc * 4 + 0);
                svals[base + slot] = __uint_as_float(u);
            }
            gpos += (gh0 >> cbit) & 1u;
            epos += (eh0 >> cbit) & 1u;
        }
        // j = 1
        {
            int slot = -1;
            if (kb1 > myp) slot = gpos;
            else if (kb1 == myp && epos < need) slot = m + epos;
            if (slot >= 0 && ok) {
                unsigned u = (__float_as_uint(acc[i][1] * ds) & 0xFFFFFF80u) | (unsigned)(cc * 4 + 1);
                svals[base + slot] = __uint_as_float(u);
            }
            gpos += (gh1 >> cbit) & 1u;
            epos += (eh1 >> cbit) & 1u;
        }
        // j = 2
        {
            int slot = -1;
            if (kb2 > myp) slot = gpos;
            else if (kb2 == myp && epos < need) slot = m + epos;
            if (slot >= 0 && ok) {
                unsigned u = (__float_as_uint(acc[i][2] * ds) & 0xFFFFFF80u) | (unsigned)(cc * 4 + 2);
                svals[base + slot] = __uint_as_float(u);
            }
            gpos += (gh2 >> cbit) & 1u;
            epos += (eh2 >> cbit) & 1u;
        }
        // j = 3
        {
            int slot = -1;
            if (kb3 > myp) slot = gpos;
            else if (kb3 == myp && epos < need) slot = m + epos;
            if (slot >= 0 && ok) {
                unsigned u = (__float_as_uint(acc[i][3] * ds) & 0xFFFFFF80u) | (unsigned)(cc * 4 + 3);
                svals[base + slot] = __uint_as_float(u);
            }
        }
    }
}

// ---------------- CSR aggregation: atomic-free ----------------
__global__ __launch_bounds__(256) void agg_kernel(const float* __restrict__ svals,
                                                  const int* __restrict__ row_off,
                                                  const int* __restrict__ csr_src,
                                                  const float* __restrict__ dvin,
                                                  const float* __restrict__ bg,
                                                  float* __restrict__ out, int n) {
    __shared__ float acc[4][2][128];  // [wave][slot][feature], wave-private
    const int wv = threadIdx.x >> 6;
    const int lane = threadIdx.x & 63;
    const int sub = lane >> 5;   // which edge slot
    const int j = lane & 31;     // entry within record
    const int node = blockIdx.x * 4 + wv;
    float* base0 = &acc[wv][0][0];
    base0[lane] = 0.f;
    base0[lane + 64] = 0.f;
    base0[lane + 128] = 0.f;
    base0[lane + 192] = 0.f;
    if (node < n) {
        int s0 = row_off[node], s1 = row_off[node + 1];
        float* Ac = &acc[wv][sub][0];
        int e = s0 + sub;
        for (; e + 2 < s1; e += 4) {
            int sA = csr_src[e];
            int sB = csr_src[e + 2];
            float vA = svals[(size_t)sA * 32 + j];
            float vB = svals[(size_t)sB * 32 + j];
            int fA = (int)(__float_as_uint(vA) & 127u);
            Ac[fA] += vA;
            int fB = (int)(__float_as_uint(vB) & 127u);
            Ac[fB] += vB;
        }
        for (; e < s1; e += 2) {
            int sA = csr_src[e];
            float vA = svals[(size_t)sA * 32 + j];
            int fA = (int)(__float_as_uint(vA) & 127u);
            Ac[fA] += vA;
        }
    }
    if (node < n) {
        float dv = dvin[node];
        float r0 = acc[wv][0][lane] + acc[wv][1][lane];
        float r1 = acc[wv][0][lane + 64] + acc[wv][1][lane + 64];
        out[(size_t)node * 128 + lane] = r0 * dv + bg[lane];
        out[(size_t)node * 128 + lane + 64] = r1 * dv + bg[lane + 64];
    }
}

// ---------------- GEMM [n,128] x [128,64] + bias -> d_out ----------------
// v4 (verified R3): 40KB LDS, (256,2), A index [kb + k].
__global__ __launch_bounds__(256, 2) void gemm_out64(const float* __restrict__ A,
                                                     const float* __restrict__ W,
                                                     const float* __restrict__ bias,
                                                     float* __restrict__ out, int n) {
    __shared__ float As[64][128];   // 32KB
    __shared__ float Ws[32][64];    // 8KB
    const int tid = threadIdx.x;
    const int rbase = blockIdx.x * 64;
    const int cc = tid & 15;
    const int r0 = (tid >> 4) * 4;
    float acc[4][4];
#pragma unroll
    for (int i = 0; i < 4; ++i) { acc[i][0] = 0.f; acc[i][1] = 0.f; acc[i][2] = 0.f; acc[i][3] = 0.f; }

    float4 wreg0 = *(const float4*)(W + (size_t)tid * 4);
    float4 wreg1 = *(const float4*)(W + (size_t)(tid + 256) * 4);

#pragma unroll
    for (int q = 0; q < 8; ++q) {
        int f = q * 256 + tid;
        *(float4*)&As[f >> 5][(f & 31) * 4] =
            *(const float4*)(A + (size_t)rbase * 128 + (size_t)f * 4);   // hbuf padded
    }

    for (int p = 0; p < 4; ++p) {
        const int kb = p * 32;
        if (p) __syncthreads();
        *(float4*)&Ws[tid >> 4][(tid & 15) * 4] = wreg0;
        *(float4*)&Ws[(tid >> 4) + 16][(tid & 15) * 4] = wreg1;
        if (p < 3) {
            const float* wp = W + (size_t)(kb + 32) * 64;
            wreg0 = *(const float4*)(wp + (size_t)tid * 4);
            wreg1 = *(const float4*)(wp + (size_t)(tid + 256) * 4);
        }
        __syncthreads();
#pragma unroll
        for (int kq = 0; kq < 8; ++kq) {
            int k = kq * 4;
            float4 w0 = *(float4*)&Ws[k + 0][cc * 4];
            float4 w1 = *(float4*)&Ws[k + 1][cc * 4];
            float4 w2 = *(float4*)&Ws[k + 2][cc * 4];
            float4 w3 = *(float4*)&Ws[k + 3][cc * 4];
#pragma unroll
            for (int i = 0; i < 4; ++i) {
                float4 a = *(float4*)&As[r0 + i][kb + k];
                acc[i][0] += a.x * w0.x + a.y * w1.x + a.z * w2.x + a.w * w3.x;
                acc[i][1] += a.x * w0.y + a.y * w1.y + a.z * w2.y + a.w * w3.y;
                acc[i][2] += a.x * w0.z + a.y * w1.z + a.z * w2.z + a.w * w3.z;
                acc[i][3] += a.x * w0.w + a.y * w1.w + a.z * w2.w + a.w * w3.w;
            }
        }
    }
    float4 b4 = *(const float4*)(bias + cc * 4);
#pragma unroll
    for (int i = 0; i < 4; ++i) {
        int gr = rbase + r0 + i;
        if (gr < n) {
            float4 o = make_float4(acc[i][0] + b4.x, acc[i][1] + b4.y,
                                   acc[i][2] + b4.z, acc[i][3] + b4.w);
            *(float4*)(out + (size_t)gr * 64 + cc * 4) = o;
        }
    }
}

extern "C" void kernel_launch(void* const* d_in, const int* in_sizes, int n_in,
                              void* d_out, int out_size, void* d_ws, size_t ws_size,
                              hipStream_t stream) {
    const float* x     = (const float*)d_in[0];
    const int*   src   = (const int*)d_in[1];
    const int*   dst   = (const int*)d_in[2];
    const float* W_in  = (const float*)d_in[3];
    const float* b_in  = (const float*)d_in[4];
    const float* W1    = (const float*)d_in[5];
    const float* b1    = (const float*)d_in[6];
    const float* bg1   = (const float*)d_in[7];
    const float* W2    = (const float*)d_in[8];
    const float* b2    = (const float*)d_in[9];
    const float* bg2   = (const float*)d_in[10];
    const float* W_out = (const float*)d_in[11];
    const float* b_out = (const float*)d_in[12];
    float* out = (float*)d_out;

    char* p = (char*)d_ws;
    auto carve = [&](size_t bytes) {
        char* r = p;
        p += (bytes + 255) & ~(size_t)255;
        return r;
    };
    int*   cnt_out = (int*)carve((size_t)NN * 4);
    int*   cnt_in  = (int*)carve((size_t)NN * 4);
    float* dvout   = (float*)carve((size_t)(NN + 128) * 4);  // padded: gemm_maxk reads OOB rows
    float* dvin    = (float*)carve((size_t)NN * 4);
    int*   incl    = (int*)carve((size_t)NN * 4);
    int*   bsums   = (int*)carve(512 * 4);
    int*   boff    = (int*)carve(512 * 4);
    int*   row_off = (int*)carve((size_t)(NN + 1) * 4);
    int*   bbase   = (int*)carve((size_t)(NBK + 1) * 4);
    int*   bcur    = (int*)carve((size_t)(NBK + 1) * 4);
    int*   csr_src = (int*)carve((size_t)EE * 4);
    float* hbuf    = (float*)carve((size_t)(NN + 128) * HIDF * 4);  // padded rows
    float* svals   = (float*)carve((size_t)NN * KSEL * 4);

    // bin[] (12.8MB) aliases hbuf (51MB): bin is consumed by csr_from_bin
    // before gemm_relu first writes hbuf (same-stream ordering).
    int2* bin = (int2*)hbuf;

    const int gN   = (NN + 255) / 256;   // 391
    const int gE   = (EE + 255) / 256;   // 6250
    const int gT   = (NN + 63) / 64;     // 1563 row tiles
    const int gAgg = (NN + 3) / 4;       // 25000

    hipMemsetAsync(cnt_out, 0, (size_t)NN * 4, stream);
    hipMemsetAsync(cnt_in, 0, (size_t)NN * 4, stream);
    hist_kernel<<<gE, 256, 0, stream>>>(src, dst, cnt_out, cnt_in, EE);
    scan_block<<<gN, 256, 0, stream>>>(cnt_in, incl, bsums, NN);
    scan_sums<<<1, 512, 0, stream>>>(bsums, boff, gN);
    finalize_offsets<<<gN, 256, 0, stream>>>(incl, boff, cnt_in, cnt_out, row_off,
                                             bbase, bcur, dvout, dvin, NN);
    bin_fill<<<gE, 256, 0, stream>>>(src, dst, bcur, bin, EE);
    csr_from_bin<<<NBK, 128, 0, stream>>>(bin, bbase, row_off, csr_src, NN);

    gemm_relu<<<gT, 256, 0, stream>>>(x, W_in, b_in, hbuf, NN);

    gemm_maxk<<<gT, 256, 0, stream>>>(hbuf, W1, b1, dvout, svals, NN);
    agg_kernel<<<gAgg, 256, 0, stream>>>(svals, row_off, csr_src, dvin, bg1, hbuf, NN);

    gemm_maxk<<<gT, 256, 0, stream>>>(hbuf, W2, b2, dvout, svals, NN);
    agg_kernel<<<gAgg, 256, 0, stream>>>(svals, row_off, csr_src, dvin, bg2, hbuf, NN);

    gemm_out64<<<gT, 256, 0, stream>>>(hbuf, W_out, b_out, out, NN);
}

// Round 6
// 700.212 us; speedup vs baseline: 1.7932x; 1.1051x over previous
//
#include <hip/hip_runtime.h>

#define NN   100000
#define EE   1600000
#define HIDF 128
#define OUTF 64
#define KSEL 32
#define BSH  3                   // log2(nodes per bucket)
#define NBK  (NN >> BSH)         // 12500 buckets (100000 = 12500*8 exact)
#define CAPSH 8                  // log2(records per bucket capacity)
#define CAP  (1 << CAPSH)        // 256 >= lambda(128) + 11 sigma

static __device__ __forceinline__ unsigned int sortable_key(float f) {
    unsigned int u = __float_as_uint(f);
    return (u & 0x80000000u) ? ~u : (u | 0x80000000u);
}

// ---------------- bin + src-degree histogram (one pass over edges) ----------------
// R5 diagnosis: hist_kernel was atomic-COUNT bound (3.2M device atomics,
// ~10.7/cy device-wide, 99.8MB atomic write-through). This version unifies
// bucket counting with bucket cursoring (fixed CAP per bucket -> no scan
// needed) and keeps only the src node histogram: 4.8M -> 3.2M atomics.
__global__ __launch_bounds__(256) void bin_fill(const int* __restrict__ src,
                                                const int* __restrict__ dst,
                                                int* __restrict__ bcnt,
                                                int* __restrict__ scnt,
                                                int2* __restrict__ bin, int e) {
    int i = blockIdx.x * 256 + threadIdx.x;
    if (i < e) {
        int s = src[i];
        int d = dst[i];
        int b = d >> BSH;
        int pos = atomicAdd(&bcnt[b], 1);
        if (pos < CAP) bin[((size_t)b << CAPSH) + pos] = make_int2(s, d);
        atomicAdd(&scnt[s], 1);
    }
}

// ---------------- per-bucket: count nodes, build row_off/cnt_in/dvin, scatter csr ----------------
// One 128-thread block per 8-node bucket. All node-level bookkeeping is
// LDS-local (no global atomics); csr layout is fixed-stride b*CAP.
__global__ __launch_bounds__(128) void csr_from_bin(const int2* __restrict__ bin,
                                                    const int* __restrict__ bcnt,
                                                    int* __restrict__ row_off,
                                                    int* __restrict__ cnt_in,
                                                    float* __restrict__ dvin,
                                                    int* __restrict__ csr, int n) {
    __shared__ int cnt8[1 << BSH];
    __shared__ int cur8[1 << BSH];
    const int b = blockIdx.x;
    const int t = threadIdx.x;
    if (t < (1 << BSH)) cnt8[t] = 0;
    __syncthreads();
    const int m = min(bcnt[b], CAP);
    const size_t base = (size_t)b << CAPSH;
    for (int e = t; e < m; e += 128) {
        atomicAdd(&cnt8[bin[base + e].y & ((1 << BSH) - 1)], 1);
    }
    __syncthreads();
    if (t < (1 << BSH)) {
        int pre = 0;
#pragma unroll
        for (int q = 0; q < (1 << BSH); ++q) pre += (q < t) ? cnt8[q] : 0;
        int node = (b << BSH) + t;
        int start = (int)base + pre;
        if (node < n) {
            row_off[node] = start;
            cnt_in[node] = cnt8[t];
            dvin[node] = rsqrtf((float)max(cnt8[t], 1));
        }
        cur8[t] = start;
    }
    __syncthreads();
    for (int e = t; e < m; e += 128) {
        int2 r = bin[base + e];
        int pos = atomicAdd(&cur8[r.y & ((1 << BSH) - 1)], 1);
        csr[pos] = r.x;
    }
}

// ---------------- dvout from src counts (dense) ----------------
__global__ __launch_bounds__(256) void dvout_pass(const int* __restrict__ scnt,
                                                  float* __restrict__ dvo, int n) {
    int i = blockIdx.x * 256 + threadIdx.x;
    if (i < n) dvo[i] = rsqrtf((float)max(scnt[i], 1));
}

// ---------------- GEMM [n,128] x [128,128] + bias + ReLU ----------------
// v4 structure (verified R3): 40KB LDS (As 32KB + Ws 16-row chunk 8KB, reg
// double-buffered W). launch_bounds (256,2): (256,4) caps VGPR at 64 -> spill.
__global__ __launch_bounds__(256, 2) void gemm_relu(const float* __restrict__ A,
                                                    const float* __restrict__ W,
                                                    const float* __restrict__ bias,
                                                    float* __restrict__ out, int n) {
    __shared__ float As[64][128];   // 32KB
    __shared__ float Ws[16][128];   // 8KB
    const int tid = threadIdx.x;
    const int rbase = blockIdx.x * 64;
    const int cc = tid & 31;
    const int r0 = (tid >> 5) * 8;
    float acc[8][4];
#pragma unroll
    for (int i = 0; i < 8; ++i) { acc[i][0] = 0.f; acc[i][1] = 0.f; acc[i][2] = 0.f; acc[i][3] = 0.f; }

    // prefetch W chunk 0 into regs (issued before A-stage loads)
    float4 wreg0 = *(const float4*)(W + (size_t)tid * 4);
    float4 wreg1 = *(const float4*)(W + (size_t)(tid + 256) * 4);

    // stage A (row-guarded: x is not padded)
#pragma unroll
    for (int q = 0; q < 8; ++q) {
        int f = q * 256 + tid;
        int row = rbase + (f >> 5);
        float4 v = make_float4(0.f, 0.f, 0.f, 0.f);
        if (row < n) v = *(const float4*)(A + (size_t)row * 128 + (f & 31) * 4);
        *(float4*)&As[f >> 5][(f & 31) * 4] = v;
    }

    for (int p = 0; p < 8; ++p) {
        const int kb = p * 16;
        if (p) __syncthreads();             // Ws of phase p-1 fully consumed
        *(float4*)&Ws[tid >> 5][(tid & 31) * 4] = wreg0;
        *(float4*)&Ws[(tid >> 5) + 8][(tid & 31) * 4] = wreg1;
        if (p < 7) {                        // issue next chunk early
            const float* wp = W + (size_t)(kb + 16) * 128;
            wreg0 = *(const float4*)(wp + (size_t)tid * 4);
            wreg1 = *(const float4*)(wp + (size_t)(tid + 256) * 4);
        }
        __syncthreads();
#pragma unroll
        for (int kq = 0; kq < 4; ++kq) {
            int k = kq * 4;
            float4 w0 = *(float4*)&Ws[k + 0][cc * 4];
            float4 w1 = *(float4*)&Ws[k + 1][cc * 4];
            float4 w2 = *(float4*)&Ws[k + 2][cc * 4];
            float4 w3 = *(float4*)&Ws[k + 3][cc * 4];
#pragma unroll
            for (int i = 0; i < 8; ++i) {
                float4 a = *(float4*)&As[r0 + i][kb + k];
                acc[i][0] += a.x * w0.x + a.y * w1.x + a.z * w2.x + a.w * w3.x;
                acc[i][1] += a.x * w0.y + a.y * w1.y + a.z * w2.y + a.w * w3.y;
                acc[i][2] += a.x * w0.z + a.y * w1.z + a.z * w2.z + a.w * w3.z;
                acc[i][3] += a.x * w0.w + a.y * w1.w + a.z * w2.w + a.w * w3.w;
            }
        }
    }
    float4 b4 = *(const float4*)(bias + cc * 4);
#pragma unroll
    for (int i = 0; i < 8; ++i) {
        int gr = rbase + r0 + i;
        if (gr < n) {
            float4 o = make_float4(fmaxf(acc[i][0] + b4.x, 0.f), fmaxf(acc[i][1] + b4.y, 0.f),
                                   fmaxf(acc[i][2] + b4.z, 0.f), fmaxf(acc[i][3] + b4.w, 0.f));
            *(float4*)(out + (size_t)gr * 128 + cc * 4) = o;
        }
    }
}

// ---------------- GEMM + bias + MaxK(top-32) fused in-register ----------------
// v4 structure (verified R3), launch_bounds (256,2).
__global__ __launch_bounds__(256, 2) void gemm_maxk(const float* __restrict__ A,
                                                    const float* __restrict__ W,
                                                    const float* __restrict__ bias,
                                                    const float* __restrict__ dvout,
                                                    float* __restrict__ svals, int n) {
    __shared__ float As[64][128];   // 32KB
    __shared__ float Ws[16][128];   // 8KB
    const int tid = threadIdx.x;
    const int rbase = blockIdx.x * 64;
    const int cc = tid & 31;
    const int r0 = (tid >> 5) * 8;
    float acc[8][4];
#pragma unroll
    for (int i = 0; i < 8; ++i) { acc[i][0] = 0.f; acc[i][1] = 0.f; acc[i][2] = 0.f; acc[i][3] = 0.f; }

    float4 wreg0 = *(const float4*)(W + (size_t)tid * 4);
    float4 wreg1 = *(const float4*)(W + (size_t)(tid + 256) * 4);

    // stage A (hbuf is row-padded: unguarded)
#pragma unroll
    for (int q = 0; q < 8; ++q) {
        int f = q * 256 + tid;
        *(float4*)&As[f >> 5][(f & 31) * 4] =
            *(const float4*)(A + (size_t)rbase * 128 + (size_t)f * 4);
    }

    for (int p = 0; p < 8; ++p) {
        const int kb = p * 16;
        if (p) __syncthreads();
        *(float4*)&Ws[tid >> 5][(tid & 31) * 4] = wreg0;
        *(float4*)&Ws[(tid >> 5) + 8][(tid & 31) * 4] = wreg1;
        if (p < 7) {
            const float* wp = W + (size_t)(kb + 16) * 128;
            wreg0 = *(const float4*)(wp + (size_t)tid * 4);
            wreg1 = *(const float4*)(wp + (size_t)(tid + 256) * 4);
        }
        __syncthreads();
#pragma unroll
        for (int kq = 0; kq < 4; ++kq) {
            int k = kq * 4;
            float4 w0 = *(float4*)&Ws[k + 0][cc * 4];
            float4 w1 = *(float4*)&Ws[k + 1][cc * 4];
            float4 w2 = *(float4*)&Ws[k + 2][cc * 4];
            float4 w3 = *(float4*)&Ws[k + 3][cc * 4];
#pragma unroll
            for (int i = 0; i < 8; ++i) {
                float4 a = *(float4*)&As[r0 + i][kb + k];
                acc[i][0] += a.x * w0.x + a.y * w1.x + a.z * w2.x + a.w * w3.x;
                acc[i][1] += a.x * w0.y + a.y * w1.y + a.z * w2.y + a.w * w3.y;
                acc[i][2] += a.x * w0.z + a.y * w1.z + a.z * w2.z + a.w * w3.z;
                acc[i][3] += a.x * w0.w + a.y * w1.w + a.z * w2.w + a.w * w3.w;
            }
        }
    }

    // ---- fused MaxK select (unchanged) ----
    const int lane = tid & 63;
    const int wvi = tid >> 6;
    const bool up = lane >= 32;
    const unsigned lt32 = (1u << (lane & 31)) - 1u;
    float4 b4 = *(const float4*)(bias + cc * 4);

    unsigned keys[8][4];
#pragma unroll
    for (int i = 0; i < 8; ++i) {
        acc[i][0] += b4.x; acc[i][1] += b4.y; acc[i][2] += b4.z; acc[i][3] += b4.w;
        keys[i][0] = sortable_key(acc[i][0]);
        keys[i][1] = sortable_key(acc[i][1]);
        keys[i][2] = sortable_key(acc[i][2]);
        keys[i][3] = sortable_key(acc[i][3]);
    }
    unsigned prefL[8], prefU[8];
#pragma unroll
    for (int i = 0; i < 8; ++i) { prefL[i] = 0u; prefU[i] = 0u; }

    for (int bit = 31; bit >= 8; --bit) {
        unsigned msk = 1u << bit;
#pragma unroll
        for (int i = 0; i < 8; ++i) {
            unsigned cL = prefL[i] | msk;
            unsigned cU = prefU[i] | msk;
            unsigned myc = up ? cU : cL;
            unsigned long long b0 = __ballot(keys[i][0] >= myc);
            unsigned long long b1 = __ballot(keys[i][1] >= myc);
            unsigned long long b2 = __ballot(keys[i][2] >= myc);
            unsigned long long b3 = __ballot(keys[i][3] >= myc);
            int cntL = __popc((unsigned)b0) + __popc((unsigned)b1) +
                       __popc((unsigned)b2) + __popc((unsigned)b3);
            int cntU = __popc((unsigned)(b0 >> 32)) + __popc((unsigned)(b1 >> 32)) +
                       __popc((unsigned)(b2 >> 32)) + __popc((unsigned)(b3 >> 32));
            prefL[i] = (cntL >= KSEL) ? cL : prefL[i];
            prefU[i] = (cntU >= KSEL) ? cU : prefU[i];
        }
    }

#pragma unroll 1
    for (int i = 0; i < 8; ++i) {
        int row = rbase + 16 * wvi + i + (up ? 8 : 0);
        unsigned myp = up ? prefU[i] : prefL[i];
        unsigned kb0 = keys[i][0] & 0xFFFFFF00u, kb1 = keys[i][1] & 0xFFFFFF00u;
        unsigned kb2 = keys[i][2] & 0xFFFFFF00u, kb3 = keys[i][3] & 0xFFFFFF00u;
        unsigned long long g0 = __ballot(kb0 > myp), g1 = __ballot(kb1 > myp);
        unsigned long long g2 = __ballot(kb2 > myp), g3 = __ballot(kb3 > myp);
        unsigned long long e0 = __ballot(kb0 == myp), e1 = __ballot(kb1 == myp);
        unsigned long long e2 = __ballot(kb2 == myp), e3 = __ballot(kb3 == myp);
        unsigned gh0 = up ? (unsigned)(g0 >> 32) : (unsigned)g0;
        unsigned gh1 = up ? (unsigned)(g1 >> 32) : (unsigned)g1;
        unsigned gh2 = up ? (unsigned)(g2 >> 32) : (unsigned)g2;
        unsigned gh3 = up ? (unsigned)(g3 >> 32) : (unsigned)g3;
        unsigned eh0 = up ? (unsigned)(e0 >> 32) : (unsigned)e0;
        unsigned eh1 = up ? (unsigned)(e1 >> 32) : (unsigned)e1;
        unsigned eh2 = up ? (unsigned)(e2 >> 32) : (unsigned)e2;
        unsigned eh3 = up ? (unsigned)(e3 >> 32) : (unsigned)e3;
        int m = __popc(gh0) + __popc(gh1) + __popc(gh2) + __popc(gh3);
        int need = KSEL - m;
        int gpos = __popc(gh0 & lt32) + __popc(gh1 & lt32) + __popc(gh2 & lt32) + __popc(gh3 & lt32);
        int epos = __popc(eh0 & lt32) + __popc(eh1 & lt32) + __popc(eh2 & lt32) + __popc(eh3 & lt32);
        bool ok = row < n;
        float ds = dvout[row];
        size_t base = (size_t)row * 32;
        unsigned cbit = (unsigned)(lane & 31);
        // j = 0
        {
            int slot = -1;
            if (kb0 > myp) slot = gpos;
            else if (kb0 == myp && epos < need) slot = m + epos;
            if (slot >= 0 && ok) {
                unsigned u = (__float_as_uint(acc[i][0] * ds) & 0xFFFFFF80u) | (unsigned)(cc * 4 + 0);
                svals[base + slot] = __uint_as_float(u);
            }
            gpos += (gh0 >> cbit) & 1u;
            epos += (eh0 >> cbit) & 1u;
        }
        // j = 1
        {
            int slot = -1;
            if (kb1 > myp) slot = gpos;
            else if (kb1 == myp && epos < need) slot = m + epos;
            if (slot >= 0 && ok) {
                unsigned u = (__float_as_uint(acc[i][1] * ds) & 0xFFFFFF80u) | (unsigned)(cc * 4 + 1);
                svals[base + slot] = __uint_as_float(u);
            }
            gpos += (gh1 >> cbit) & 1u;
            epos += (eh1 >> cbit) & 1u;
        }
        // j = 2
        {
            int slot = -1;
            if (kb2 > myp) slot = gpos;
            else if (kb2 == myp && epos < need) slot = m + epos;
            if (slot >= 0 && ok) {
                unsigned u = (__float_as_uint(acc[i][2] * ds) & 0xFFFFFF80u) | (unsigned)(cc * 4 + 2);
                svals[base + slot] = __uint_as_float(u);
            }
            gpos += (gh2 >> cbit) & 1u;
            epos += (eh2 >> cbit) & 1u;
        }
        // j = 3
        {
            int slot = -1;
            if (kb3 > myp) slot = gpos;
            else if (kb3 == myp && epos < need) slot = m + epos;
            if (slot >= 0 && ok) {
                unsigned u = (__float_as_uint(acc[i][3] * ds) & 0xFFFFFF80u) | (unsigned)(cc * 4 + 3);
                svals[base + slot] = __uint_as_float(u);
            }
        }
    }
}

// ---------------- CSR aggregation: atomic-free ----------------
// v6: s1 = s0 + cnt_in[node] (csr is fixed-stride per bucket -> row_off[node+1]
// no longer adjacent).
__global__ __launch_bounds__(256) void agg_kernel(const float* __restrict__ svals,
                                                  const int* __restrict__ row_off,
                                                  const int* __restrict__ cnt_in,
                                                  const int* __restrict__ csr_src,
                                                  const float* __restrict__ dvin,
                                                  const float* __restrict__ bg,
                                                  float* __restrict__ out, int n) {
    __shared__ float acc[4][2][128];  // [wave][slot][feature], wave-private
    const int wv = threadIdx.x >> 6;
    const int lane = threadIdx.x & 63;
    const int sub = lane >> 5;   // which edge slot
    const int j = lane & 31;     // entry within record
    const int node = blockIdx.x * 4 + wv;
    float* base0 = &acc[wv][0][0];
    base0[lane] = 0.f;
    base0[lane + 64] = 0.f;
    base0[lane + 128] = 0.f;
    base0[lane + 192] = 0.f;
    if (node < n) {
        int s0 = row_off[node], s1 = s0 + cnt_in[node];
        float* Ac = &acc[wv][sub][0];
        int e = s0 + sub;
        for (; e + 2 < s1; e += 4) {
            int sA = csr_src[e];
            int sB = csr_src[e + 2];
            float vA = svals[(size_t)sA * 32 + j];
            float vB = svals[(size_t)sB * 32 + j];
            int fA = (int)(__float_as_uint(vA) & 127u);
            Ac[fA] += vA;
            int fB = (int)(__float_as_uint(vB) & 127u);
            Ac[fB] += vB;
        }
        for (; e < s1; e += 2) {
            int sA = csr_src[e];
            float vA = svals[(size_t)sA * 32 + j];
            int fA = (int)(__float_as_uint(vA) & 127u);
            Ac[fA] += vA;
        }
    }
    if (node < n) {
        float dv = dvin[node];
        float r0 = acc[wv][0][lane] + acc[wv][1][lane];
        float r1 = acc[wv][0][lane + 64] + acc[wv][1][lane + 64];
        out[(size_t)node * 128 + lane] = r0 * dv + bg[lane];
        out[(size_t)node * 128 + lane + 64] = r1 * dv + bg[lane + 64];
    }
}

// ---------------- GEMM [n,128] x [128,64] + bias -> d_out ----------------
// v4 (verified R3): 40KB LDS, (256,2), A index [kb + k].
__global__ __launch_bounds__(256, 2) void gemm_out64(const float* __restrict__ A,
                                                     const float* __restrict__ W,
                                                     const float* __restrict__ bias,
                                                     float* __restrict__ out, int n) {
    __shared__ float As[64][128];   // 32KB
    __shared__ float Ws[32][64];    // 8KB
    const int tid = threadIdx.x;
    const int rbase = blockIdx.x * 64;
    const int cc = tid & 15;
    const int r0 = (tid >> 4) * 4;
    float acc[4][4];
#pragma unroll
    for (int i = 0; i < 4; ++i) { acc[i][0] = 0.f; acc[i][1] = 0.f; acc[i][2] = 0.f; acc[i][3] = 0.f; }

    float4 wreg0 = *(const float4*)(W + (size_t)tid * 4);
    float4 wreg1 = *(const float4*)(W + (size_t)(tid + 256) * 4);

#pragma unroll
    for (int q = 0; q < 8; ++q) {
        int f = q * 256 + tid;
        *(float4*)&As[f >> 5][(f & 31) * 4] =
            *(const float4*)(A + (size_t)rbase * 128 + (size_t)f * 4);   // hbuf padded
    }

    for (int p = 0; p < 4; ++p) {
        const int kb = p * 32;
        if (p) __syncthreads();
        *(float4*)&Ws[tid >> 4][(tid & 15) * 4] = wreg0;
        *(float4*)&Ws[(tid >> 4) + 16][(tid & 15) * 4] = wreg1;
        if (p < 3) {
            const float* wp = W + (size_t)(kb + 32) * 64;
            wreg0 = *(const float4*)(wp + (size_t)tid * 4);
            wreg1 = *(const float4*)(wp + (size_t)(tid + 256) * 4);
        }
        __syncthreads();
#pragma unroll
        for (int kq = 0; kq < 8; ++kq) {
            int k = kq * 4;
            float4 w0 = *(float4*)&Ws[k + 0][cc * 4];
            float4 w1 = *(float4*)&Ws[k + 1][cc * 4];
            float4 w2 = *(float4*)&Ws[k + 2][cc * 4];
            float4 w3 = *(float4*)&Ws[k + 3][cc * 4];
#pragma unroll
            for (int i = 0; i < 4; ++i) {
                float4 a = *(float4*)&As[r0 + i][kb + k];
                acc[i][0] += a.x * w0.x + a.y * w1.x + a.z * w2.x + a.w * w3.x;
                acc[i][1] += a.x * w0.y + a.y * w1.y + a.z * w2.y + a.w * w3.y;
                acc[i][2] += a.x * w0.z + a.y * w1.z + a.z * w2.z + a.w * w3.z;
                acc[i][3] += a.x * w0.w + a.y * w1.w + a.z * w2.w + a.w * w3.w;
            }
        }
    }
    float4 b4 = *(const float4*)(bias + cc * 4);
#pragma unroll
    for (int i = 0; i < 4; ++i) {
        int gr = rbase + r0 + i;
        if (gr < n) {
            float4 o = make_float4(acc[i][0] + b4.x, acc[i][1] + b4.y,
                                   acc[i][2] + b4.z, acc[i][3] + b4.w);
            *(float4*)(out + (size_t)gr * 64 + cc * 4) = o;
        }
    }
}

extern "C" void kernel_launch(void* const* d_in, const int* in_sizes, int n_in,
                              void* d_out, int out_size, void* d_ws, size_t ws_size,
                              hipStream_t stream) {
    const float* x     = (const float*)d_in[0];
    const int*   src   = (const int*)d_in[1];
    const int*   dst   = (const int*)d_in[2];
    const float* W_in  = (const float*)d_in[3];
    const float* b_in  = (const float*)d_in[4];
    const float* W1    = (const float*)d_in[5];
    const float* b1    = (const float*)d_in[6];
    const float* bg1   = (const float*)d_in[7];
    const float* W2    = (const float*)d_in[8];
    const float* b2    = (const float*)d_in[9];
    const float* bg2   = (const float*)d_in[10];
    const float* W_out = (const float*)d_in[11];
    const float* b_out = (const float*)d_in[12];
    float* out = (float*)d_out;

    char* p = (char*)d_ws;
    auto carve = [&](size_t bytes) {
        char* r = p;
        p += (bytes + 255) & ~(size_t)255;
        return r;
    };
    int*   scnt    = (int*)carve((size_t)NN * 4);
    int*   bcnt    = (int*)carve((size_t)NBK * 4);
    float* dvout   = (float*)carve((size_t)(NN + 128) * 4);  // padded: gemm_maxk reads OOB rows
    float* dvin    = (float*)carve((size_t)NN * 4);
    int*   row_off = (int*)carve((size_t)NN * 4);
    int*   cnt_in  = (int*)carve((size_t)NN * 4);
    int*   csr_src = (int*)carve((size_t)NBK * CAP * 4);     // 12.8MB fixed-stride
    float* hbuf    = (float*)carve((size_t)(NN + 128) * HIDF * 4);  // padded rows
    float* svals   = (float*)carve((size_t)NN * KSEL * 4);

    // bin[] (25.6MB) aliases hbuf (51.3MB): bin is consumed by csr_from_bin
    // before gemm_relu first writes hbuf (same-stream ordering).
    int2* bin = (int2*)hbuf;

    const int gN   = (NN + 255) / 256;   // 391
    const int gE   = (EE + 255) / 256;   // 6250
    const int gT   = (NN + 63) / 64;     // 1563 row tiles
    const int gAgg = (NN + 3) / 4;       // 25000

    hipMemsetAsync(scnt, 0, (size_t)NN * 4, stream);
    hipMemsetAsync(bcnt, 0, (size_t)NBK * 4, stream);
    bin_fill<<<gE, 256, 0, stream>>>(src, dst, bcnt, scnt, bin, EE);
    csr_from_bin<<<NBK, 128, 0, stream>>>(bin, bcnt, row_off, cnt_in, dvin, csr_src, NN);
    dvout_pass<<<gN, 256, 0, stream>>>(scnt, dvout, NN);

    gemm_relu<<<gT, 256, 0, stream>>>(x, W_in, b_in, hbuf, NN);

    gemm_maxk<<<gT, 256, 0, stream>>>(hbuf, W1, b1, dvout, svals, NN);
    agg_kernel<<<gAgg, 256, 0, stream>>>(svals, row_off, cnt_in, csr_src, dvin, bg1, hbuf, NN);

    gemm_maxk<<<gT, 256, 0, stream>>>(hbuf, W2, b2, dvout, svals, NN);
    agg_kernel<<<gAgg, 256, 0, stream>>>(svals, row_off, cnt_in, csr_src, dvin, bg2, hbuf, NN);

    gemm_out64<<<gT, 256, 0, stream>>>(hbuf, W_out, b_out, out, NN);
}

// Round 7
// 683.323 us; speedup vs baseline: 1.8375x; 1.0247x over previous
//
#include <hip/hip_runtime.h>

#define NN   100000
#define EE   1600000
#define HIDF 128
#define OUTF 64
#define KSEL 32
#define BSH  3                   // log2(nodes per bucket)
#define NBK  (NN >> BSH)         // 12500 buckets (100000 = 12500*8 exact)
#define CAPSH 8                  // log2(records per bucket capacity)
#define CAP  (1 << CAPSH)        // 256; Poisson(128) max over 12500 buckets ~ 177
#define GT   ((NN + 63) / 64)    // 1563 gemm row tiles
#define GE   ((EE + 255) / 256)  // 6250 edge blocks

static __device__ __forceinline__ unsigned int sortable_key(float f) {
    unsigned int u = __float_as_uint(f);
    return (u & 0x80000000u) ? ~u : (u | 0x80000000u);
}

// ================= fused K1: edge binning (atomic-bound) + input GEMM (VALU-bound) =================
// R6 diagnosis: bin_fill is at the device atomic-throughput floor (3.2M atomics,
// ~46ns each, VALU 0.4%, HBM 12%) -> the only lever left is OVERLAP. gemm_relu
// has no data dependence on the CSR build and uses disjoint HW (VALU+LDS).
// Bin blocks dispatched FIRST so the atomic stream starts immediately; relu
// tiles fill the remaining CU slots and compute under the atomic latency.
// bin record packed to one int: (src<<3)|(dst&7) -- halves bin traffic and
// un-aliases bin from hbuf (both written concurrently here).
__global__ __launch_bounds__(256, 2) void fused_bin_relu(const int* __restrict__ src,
                                                         const int* __restrict__ dst,
                                                         int* __restrict__ bcnt,
                                                         int* __restrict__ scnt,
                                                         int* __restrict__ bin,
                                                         const float* __restrict__ X,
                                                         const float* __restrict__ W,
                                                         const float* __restrict__ bias,
                                                         float* __restrict__ out) {
    __shared__ float As[64][128];   // 32KB (gemm branch only)
    __shared__ float Ws[16][128];   // 8KB
    const int tid = threadIdx.x;

    if (blockIdx.x < GE) {
        // ---- bin branch ----
        int i = blockIdx.x * 256 + tid;
        if (i < EE) {
            int s = src[i];
            int d = dst[i];
            int b = d >> BSH;
            int pos = atomicAdd(&bcnt[b], 1);
            if (pos < CAP) bin[(b << CAPSH) + pos] = (s << BSH) | (d & ((1 << BSH) - 1));
            atomicAdd(&scnt[s], 1);
        }
        return;
    }

    // ---- gemm_relu branch (verified R3 body; 40KB LDS, reg-dbuf W chunks) ----
    const int rbase = (blockIdx.x - GE) * 64;
    const int cc = tid & 31;
    const int r0 = (tid >> 5) * 8;
    const int n = NN;
    float acc[8][4];
#pragma unroll
    for (int i = 0; i < 8; ++i) { acc[i][0] = 0.f; acc[i][1] = 0.f; acc[i][2] = 0.f; acc[i][3] = 0.f; }

    float4 wreg0 = *(const float4*)(W + (size_t)tid * 4);
    float4 wreg1 = *(const float4*)(W + (size_t)(tid + 256) * 4);

    // stage A (row-guarded: x is not padded)
#pragma unroll
    for (int q = 0; q < 8; ++q) {
        int f = q * 256 + tid;
        int row = rbase + (f >> 5);
        float4 v = make_float4(0.f, 0.f, 0.f, 0.f);
        if (row < n) v = *(const float4*)(X + (size_t)row * 128 + (f & 31) * 4);
        *(float4*)&As[f >> 5][(f & 31) * 4] = v;
    }

    for (int p = 0; p < 8; ++p) {
        const int kb = p * 16;
        if (p) __syncthreads();
        *(float4*)&Ws[tid >> 5][(tid & 31) * 4] = wreg0;
        *(float4*)&Ws[(tid >> 5) + 8][(tid & 31) * 4] = wreg1;
        if (p < 7) {
            const float* wp = W + (size_t)(kb + 16) * 128;
            wreg0 = *(const float4*)(wp + (size_t)tid * 4);
            wreg1 = *(const float4*)(wp + (size_t)(tid + 256) * 4);
        }
        __syncthreads();
#pragma unroll
        for (int kq = 0; kq < 4; ++kq) {
            int k = kq * 4;
            float4 w0 = *(float4*)&Ws[k + 0][cc * 4];
            float4 w1 = *(float4*)&Ws[k + 1][cc * 4];
            float4 w2 = *(float4*)&Ws[k + 2][cc * 4];
            float4 w3 = *(float4*)&Ws[k + 3][cc * 4];
#pragma unroll
            for (int i = 0; i < 8; ++i) {
                float4 a = *(float4*)&As[r0 + i][kb + k];
                acc[i][0] += a.x * w0.x + a.y * w1.x + a.z * w2.x + a.w * w3.x;
                acc[i][1] += a.x * w0.y + a.y * w1.y + a.z * w2.y + a.w * w3.y;
                acc[i][2] += a.x * w0.z + a.y * w1.z + a.z * w2.z + a.w * w3.z;
                acc[i][3] += a.x * w0.w + a.y * w1.w + a.z * w2.w + a.w * w3.w;
            }
        }
    }
    float4 b4 = *(const float4*)(bias + cc * 4);
#pragma unroll
    for (int i = 0; i < 8; ++i) {
        int gr = rbase + r0 + i;
        if (gr < n) {
            float4 o = make_float4(fmaxf(acc[i][0] + b4.x, 0.f), fmaxf(acc[i][1] + b4.y, 0.f),
                                   fmaxf(acc[i][2] + b4.z, 0.f), fmaxf(acc[i][3] + b4.w, 0.f));
            *(float4*)(out + (size_t)gr * 128 + cc * 4) = o;
        }
    }
}

// ================= gemm_maxk body (shared by fused K2 and standalone layer-2) =================
// v7: dvout no longer precomputed -- ds = rsqrtf(scnt[row]) inline (identical
// value; removes the dvout_pass dependency so csr build can fuse under maxk#1).
static __device__ __forceinline__ void gemm_maxk_body(float (*As)[128], float (*Ws)[128],
                                                      const float* __restrict__ A,
                                                      const float* __restrict__ W,
                                                      const float* __restrict__ bias,
                                                      const int* __restrict__ scnt,
                                                      float* __restrict__ svals,
                                                      int n, int rbase) {
    const int tid = threadIdx.x;
    const int cc = tid & 31;
    const int r0 = (tid >> 5) * 8;
    float acc[8][4];
#pragma unroll
    for (int i = 0; i < 8; ++i) { acc[i][0] = 0.f; acc[i][1] = 0.f; acc[i][2] = 0.f; acc[i][3] = 0.f; }

    float4 wreg0 = *(const float4*)(W + (size_t)tid * 4);
    float4 wreg1 = *(const float4*)(W + (size_t)(tid + 256) * 4);

    // stage A (hbuf is row-padded: unguarded)
#pragma unroll
    for (int q = 0; q < 8; ++q) {
        int f = q * 256 + tid;
        *(float4*)&As[f >> 5][(f & 31) * 4] =
            *(const float4*)(A + (size_t)rbase * 128 + (size_t)f * 4);
    }

    for (int p = 0; p < 8; ++p) {
        const int kb = p * 16;
        if (p) __syncthreads();
        *(float4*)&Ws[tid >> 5][(tid & 31) * 4] = wreg0;
        *(float4*)&Ws[(tid >> 5) + 8][(tid & 31) * 4] = wreg1;
        if (p < 7) {
            const float* wp = W + (size_t)(kb + 16) * 128;
            wreg0 = *(const float4*)(wp + (size_t)tid * 4);
            wreg1 = *(const float4*)(wp + (size_t)(tid + 256) * 4);
        }
        __syncthreads();
#pragma unroll
        for (int kq = 0; kq < 4; ++kq) {
            int k = kq * 4;
            float4 w0 = *(float4*)&Ws[k + 0][cc * 4];
            float4 w1 = *(float4*)&Ws[k + 1][cc * 4];
            float4 w2 = *(float4*)&Ws[k + 2][cc * 4];
            float4 w3 = *(float4*)&Ws[k + 3][cc * 4];
#pragma unroll
            for (int i = 0; i < 8; ++i) {
                float4 a = *(float4*)&As[r0 + i][kb + k];
                acc[i][0] += a.x * w0.x + a.y * w1.x + a.z * w2.x + a.w * w3.x;
                acc[i][1] += a.x * w0.y + a.y * w1.y + a.z * w2.y + a.w * w3.y;
                acc[i][2] += a.x * w0.z + a.y * w1.z + a.z * w2.z + a.w * w3.z;
                acc[i][3] += a.x * w0.w + a.y * w1.w + a.z * w2.w + a.w * w3.w;
            }
        }
    }

    // ---- fused MaxK select (verified R0 logic) ----
    const int lane = tid & 63;
    const int wvi = tid >> 6;
    const bool up = lane >= 32;
    const unsigned lt32 = (1u << (lane & 31)) - 1u;
    float4 b4 = *(const float4*)(bias + cc * 4);

    unsigned keys[8][4];
#pragma unroll
    for (int i = 0; i < 8; ++i) {
        acc[i][0] += b4.x; acc[i][1] += b4.y; acc[i][2] += b4.z; acc[i][3] += b4.w;
        keys[i][0] = sortable_key(acc[i][0]);
        keys[i][1] = sortable_key(acc[i][1]);
        keys[i][2] = sortable_key(acc[i][2]);
        keys[i][3] = sortable_key(acc[i][3]);
    }
    unsigned prefL[8], prefU[8];
#pragma unroll
    for (int i = 0; i < 8; ++i) { prefL[i] = 0u; prefU[i] = 0u; }

    for (int bit = 31; bit >= 8; --bit) {
        unsigned msk = 1u << bit;
#pragma unroll
        for (int i = 0; i < 8; ++i) {
            unsigned cL = prefL[i] | msk;
            unsigned cU = prefU[i] | msk;
            unsigned myc = up ? cU : cL;
            unsigned long long b0 = __ballot(keys[i][0] >= myc);
            unsigned long long b1 = __ballot(keys[i][1] >= myc);
            unsigned long long b2 = __ballot(keys[i][2] >= myc);
            unsigned long long b3 = __ballot(keys[i][3] >= myc);
            int cntL = __popc((unsigned)b0) + __popc((unsigned)b1) +
                       __popc((unsigned)b2) + __popc((unsigned)b3);
            int cntU = __popc((unsigned)(b0 >> 32)) + __popc((unsigned)(b1 >> 32)) +
                       __popc((unsigned)(b2 >> 32)) + __popc((unsigned)(b3 >> 32));
            prefL[i] = (cntL >= KSEL) ? cL : prefL[i];
            prefU[i] = (cntU >= KSEL) ? cU : prefU[i];
        }
    }

#pragma unroll 1
    for (int i = 0; i < 8; ++i) {
        int row = rbase + 16 * wvi + i + (up ? 8 : 0);
        unsigned myp = up ? prefU[i] : prefL[i];
        unsigned kb0 = keys[i][0] & 0xFFFFFF00u, kb1 = keys[i][1] & 0xFFFFFF00u;
        unsigned kb2 = keys[i][2] & 0xFFFFFF00u, kb3 = keys[i][3] & 0xFFFFFF00u;
        unsigned long long g0 = __ballot(kb0 > myp), g1 = __ballot(kb1 > myp);
        unsigned long long g2 = __ballot(kb2 > myp), g3 = __ballot(kb3 > myp);
        unsigned long long e0 = __ballot(kb0 == myp), e1 = __ballot(kb1 == myp);
        unsigned long long e2 = __ballot(kb2 == myp), e3 = __ballot(kb3 == myp);
        unsigned gh0 = up ? (unsigned)(g0 >> 32) : (unsigned)g0;
        unsigned gh1 = up ? (unsigned)(g1 >> 32) : (unsigned)g1;
        unsigned gh2 = up ? (unsigned)(g2 >> 32) : (unsigned)g2;
        unsigned gh3 = up ? (unsigned)(g3 >> 32) : (unsigned)g3;
        unsigned eh0 = up ? (unsigned)(e0 >> 32) : (unsigned)e0;
        unsigned eh1 = up ? (unsigned)(e1 >> 32) : (unsigned)e1;
        unsigned eh2 = up ? (unsigned)(e2 >> 32) : (unsigned)e2;
        unsigned eh3 = up ? (unsigned)(e3 >> 32) : (unsigned)e3;
        int m = __popc(gh0) + __popc(gh1) + __popc(gh2) + __popc(gh3);
        int need = KSEL - m;
        int gpos = __popc(gh0 & lt32) + __popc(gh1 & lt32) + __popc(gh2 & lt32) + __popc(gh3 & lt32);
        int epos = __popc(eh0 & lt32) + __popc(eh1 & lt32) + __popc(eh2 & lt32) + __popc(eh3 & lt32);
        bool ok = row < n;
        float ds = 0.f;
        if (ok) ds = rsqrtf((float)max(scnt[row], 1));
        size_t base = (size_t)row * 32;
        unsigned cbit = (unsigned)(lane & 31);
        // j = 0
        {
            int slot = -1;
            if (kb0 > myp) slot = gpos;
            else if (kb0 == myp && epos < need) slot = m + epos;
            if (slot >= 0 && ok) {
                unsigned u = (__float_as_uint(acc[i][0] * ds) & 0xFFFFFF80u) | (unsigned)(cc * 4 + 0);
                svals[base + slot] = __uint_as_float(u);
            }
            gpos += (gh0 >> cbit) & 1u;
            epos += (eh0 >> cbit) & 1u;
        }
        // j = 1
        {
            int slot = -1;
            if (kb1 > myp) slot = gpos;
            else if (kb1 == myp && epos < need) slot = m + epos;
            if (slot >= 0 && ok) {
                unsigned u = (__float_as_uint(acc[i][1] * ds) & 0xFFFFFF80u) | (unsigned)(cc * 4 + 1);
                svals[base + slot] = __uint_as_float(u);
            }
            gpos += (gh1 >> cbit) & 1u;
            epos += (eh1 >> cbit) & 1u;
        }
        // j = 2
        {
            int slot = -1;
            if (kb2 > myp) slot = gpos;
            else if (kb2 == myp && epos < need) slot = m + epos;
            if (slot >= 0 && ok) {
                unsigned u = (__float_as_uint(acc[i][2] * ds) & 0xFFFFFF80u) | (unsigned)(cc * 4 + 2);
                svals[base + slot] = __uint_as_float(u);
            }
            gpos += (gh2 >> cbit) & 1u;
            epos += (eh2 >> cbit) & 1u;
        }
        // j = 3
        {
            int slot = -1;
            if (kb3 > myp) slot = gpos;
            else if (kb3 == myp && epos < need) slot = m + epos;
            if (slot >= 0 && ok) {
                unsigned u = (__float_as_uint(acc[i][3] * ds) & 0xFFFFFF80u) | (unsigned)(cc * 4 + 3);
                svals[base + slot] = __uint_as_float(u);
            }
        }
    }
}

// ================= fused K2: gemm_maxk#1 (long) + csr_from_bin (short, hidden under it) =================
// maxk tiles first (long-running, fill CUs early); 12500 short csr blocks
// drain in the gaps/tail. csr branch reuses the gemm LDS as its 8-counter
// scratch. All csr outputs are consumed only by the NEXT kernel (agg).
__global__ __launch_bounds__(256, 2) void fused_csr_maxk(const int* __restrict__ bin,
                                                         const int* __restrict__ bcnt,
                                                         int* __restrict__ row_off,
                                                         int* __restrict__ cnt_in,
                                                         float* __restrict__ dvin,
                                                         int* __restrict__ csr,
                                                         const float* __restrict__ A,
                                                         const float* __restrict__ W,
                                                         const float* __restrict__ bias,
                                                         const int* __restrict__ scnt,
                                                         float* __restrict__ svals) {
    __shared__ float As[64][128];
    __shared__ float Ws[16][128];
    const int tid = threadIdx.x;

    if (blockIdx.x >= GT) {
        // ---- csr branch: per-bucket node counts, offsets, scatter ----
        int* cnt8 = (int*)&As[0][0];
        int* cur8 = cnt8 + (1 << BSH);
        const int b = blockIdx.x - GT;
        if (tid < (1 << BSH)) cnt8[tid] = 0;
        __syncthreads();
        const int m = min(bcnt[b], CAP);
        const int base = b << CAPSH;
        for (int e = tid; e < m; e += 256) {
            atomicAdd(&cnt8[bin[base + e] & ((1 << BSH) - 1)], 1);
        }
        __syncthreads();
        if (tid < (1 << BSH)) {
            int pre = 0;
#pragma unroll
            for (int q = 0; q < (1 << BSH); ++q) pre += (q < tid) ? cnt8[q] : 0;
            int node = (b << BSH) + tid;
            int start = base + pre;
            if (node < NN) {
                row_off[node] = start;
                cnt_in[node] = cnt8[tid];
                dvin[node] = rsqrtf((float)max(cnt8[tid], 1));
            }
            cur8[tid] = start;
        }
        __syncthreads();
        for (int e = tid; e < m; e += 256) {
            int r = bin[base + e];
            int pos = atomicAdd(&cur8[r & ((1 << BSH) - 1)], 1);
            csr[pos] = r >> BSH;
        }
        return;
    }

    gemm_maxk_body(As, Ws, A, W, bias, scnt, svals, NN, blockIdx.x * 64);
}

// ================= standalone gemm_maxk (layer 2) =================
__global__ __launch_bounds__(256, 2) void gemm_maxk(const float* __restrict__ A,
                                                    const float* __restrict__ W,
                                                    const float* __restrict__ bias,
                                                    const int* __restrict__ scnt,
                                                    float* __restrict__ svals, int n) {
    __shared__ float As[64][128];
    __shared__ float Ws[16][128];
    gemm_maxk_body(As, Ws, A, W, bias, scnt, svals, n, blockIdx.x * 64);
}

// ---------------- CSR aggregation: atomic-free (unchanged from R6) ----------------
__global__ __launch_bounds__(256) void agg_kernel(const float* __restrict__ svals,
                                                  const int* __restrict__ row_off,
                                                  const int* __restrict__ cnt_in,
                                                  const int* __restrict__ csr_src,
                                                  const float* __restrict__ dvin,
                                                  const float* __restrict__ bg,
                                                  float* __restrict__ out, int n) {
    __shared__ float acc[4][2][128];  // [wave][slot][feature], wave-private
    const int wv = threadIdx.x >> 6;
    const int lane = threadIdx.x & 63;
    const int sub = lane >> 5;   // which edge slot
    const int j = lane & 31;     // entry within record
    const int node = blockIdx.x * 4 + wv;
    float* base0 = &acc[wv][0][0];
    base0[lane] = 0.f;
    base0[lane + 64] = 0.f;
    base0[lane + 128] = 0.f;
    base0[lane + 192] = 0.f;
    if (node < n) {
        int s0 = row_off[node], s1 = s0 + cnt_in[node];
        float* Ac = &acc[wv][sub][0];
        int e = s0 + sub;
        for (; e + 2 < s1; e += 4) {
            int sA = csr_src[e];
            int sB = csr_src[e + 2];
            float vA = svals[(size_t)sA * 32 + j];
            float vB = svals[(size_t)sB * 32 + j];
            int fA = (int)(__float_as_uint(vA) & 127u);
            Ac[fA] += vA;
            int fB = (int)(__float_as_uint(vB) & 127u);
            Ac[fB] += vB;
        }
        for (; e < s1; e += 2) {
            int sA = csr_src[e];
            float vA = svals[(size_t)sA * 32 + j];
            int fA = (int)(__float_as_uint(vA) & 127u);
            Ac[fA] += vA;
        }
    }
    if (node < n) {
        float dv = dvin[node];
        float r0 = acc[wv][0][lane] + acc[wv][1][lane];
        float r1 = acc[wv][0][lane + 64] + acc[wv][1][lane + 64];
        out[(size_t)node * 128 + lane] = r0 * dv + bg[lane];
        out[(size_t)node * 128 + lane + 64] = r1 * dv + bg[lane + 64];
    }
}

// ---------------- GEMM [n,128] x [128,64] + bias -> d_out (unchanged, verified R3) ----------------
__global__ __launch_bounds__(256, 2) void gemm_out64(const float* __restrict__ A,
                                                     const float* __restrict__ W,
                                                     const float* __restrict__ bias,
                                                     float* __restrict__ out, int n) {
    __shared__ float As[64][128];   // 32KB
    __shared__ float Ws[32][64];    // 8KB
    const int tid = threadIdx.x;
    const int rbase = blockIdx.x * 64;
    const int cc = tid & 15;
    const int r0 = (tid >> 4) * 4;
    float acc[4][4];
#pragma unroll
    for (int i = 0; i < 4; ++i) { acc[i][0] = 0.f; acc[i][1] = 0.f; acc[i][2] = 0.f; acc[i][3] = 0.f; }

    float4 wreg0 = *(const float4*)(W + (size_t)tid * 4);
    float4 wreg1 = *(const float4*)(W + (size_t)(tid + 256) * 4);

#pragma unroll
    for (int q = 0; q < 8; ++q) {
        int f = q * 256 + tid;
        *(float4*)&As[f >> 5][(f & 31) * 4] =
            *(const float4*)(A + (size_t)rbase * 128 + (size_t)f * 4);   // hbuf padded
    }

    for (int p = 0; p < 4; ++p) {
        const int kb = p * 32;
        if (p) __syncthreads();
        *(float4*)&Ws[tid >> 4][(tid & 15) * 4] = wreg0;
        *(float4*)&Ws[(tid >> 4) + 16][(tid & 15) * 4] = wreg1;
        if (p < 3) {
            const float* wp = W + (size_t)(kb + 32) * 64;
            wreg0 = *(const float4*)(wp + (size_t)tid * 4);
            wreg1 = *(const float4*)(wp + (size_t)(tid + 256) * 4);
        }
        __syncthreads();
#pragma unroll
        for (int kq = 0; kq < 8; ++kq) {
            int k = kq * 4;
            float4 w0 = *(float4*)&Ws[k + 0][cc * 4];
            float4 w1 = *(float4*)&Ws[k + 1][cc * 4];
            float4 w2 = *(float4*)&Ws[k + 2][cc * 4];
            float4 w3 = *(float4*)&Ws[k + 3][cc * 4];
#pragma unroll
            for (int i = 0; i < 4; ++i) {
                float4 a = *(float4*)&As[r0 + i][kb + k];
                acc[i][0] += a.x * w0.x + a.y * w1.x + a.z * w2.x + a.w * w3.x;
                acc[i][1] += a.x * w0.y + a.y * w1.y + a.z * w2.y + a.w * w3.y;
                acc[i][2] += a.x * w0.z + a.y * w1.z + a.z * w2.z + a.w * w3.z;
                acc[i][3] += a.x * w0.w + a.y * w1.w + a.z * w2.w + a.w * w3.w;
            }
        }
    }
    float4 b4 = *(const float4*)(bias + cc * 4);
#pragma unroll
    for (int i = 0; i < 4; ++i) {
        int gr = rbase + r0 + i;
        if (gr < n) {
            float4 o = make_float4(acc[i][0] + b4.x, acc[i][1] + b4.y,
                                   acc[i][2] + b4.z, acc[i][3] + b4.w);
            *(float4*)(out + (size_t)gr * 64 + cc * 4) = o;
        }
    }
}

extern "C" void kernel_launch(void* const* d_in, const int* in_sizes, int n_in,
                              void* d_out, int out_size, void* d_ws, size_t ws_size,
                              hipStream_t stream) {
    const float* x     = (const float*)d_in[0];
    const int*   src   = (const int*)d_in[1];
    const int*   dst   = (const int*)d_in[2];
    const float* W_in  = (const float*)d_in[3];
    const float* b_in  = (const float*)d_in[4];
    const float* W1    = (const float*)d_in[5];
    const float* b1    = (const float*)d_in[6];
    const float* bg1   = (const float*)d_in[7];
    const float* W2    = (const float*)d_in[8];
    const float* b2    = (const float*)d_in[9];
    const float* bg2   = (const float*)d_in[10];
    const float* W_out = (const float*)d_in[11];
    const float* b_out = (const float*)d_in[12];
    float* out = (float*)d_out;

    char* p = (char*)d_ws;
    auto carve = [&](size_t bytes) {
        char* r = p;
        p += (bytes + 255) & ~(size_t)255;
        return r;
    };
    int*   scnt    = (int*)carve((size_t)NN * 4);
    int*   bcnt    = (int*)carve((size_t)NBK * 4);
    float* dvin    = (float*)carve((size_t)NN * 4);
    int*   row_off = (int*)carve((size_t)NN * 4);
    int*   cnt_in  = (int*)carve((size_t)NN * 4);
    int*   bin     = (int*)carve((size_t)NBK * CAP * 4);     // 12.8MB packed records
    int*   csr_src = (int*)carve((size_t)NBK * CAP * 4);     // 12.8MB fixed-stride
    float* hbuf    = (float*)carve((size_t)(NN + 128) * HIDF * 4);  // padded rows
    float* svals   = (float*)carve((size_t)NN * KSEL * 4);

    const int gAgg = (NN + 3) / 4;       // 25000

    hipMemsetAsync(scnt, 0, (size_t)NN * 4, stream);
    hipMemsetAsync(bcnt, 0, (size_t)NBK * 4, stream);

    // K1: binning (atomic stream) overlapped with input GEMM (VALU stream)
    fused_bin_relu<<<GE + GT, 256, 0, stream>>>(src, dst, bcnt, scnt, bin,
                                                x, W_in, b_in, hbuf);
    // K2: layer-1 GEMM+MaxK overlapped with CSR materialization
    fused_csr_maxk<<<GT + NBK, 256, 0, stream>>>(bin, bcnt, row_off, cnt_in, dvin, csr_src,
                                                 hbuf, W1, b1, scnt, svals);
    agg_kernel<<<gAgg, 256, 0, stream>>>(svals, row_off, cnt_in, csr_src, dvin, bg1, hbuf, NN);

    gemm_maxk<<<GT, 256, 0, stream>>>(hbuf, W2, b2, scnt, svals, NN);
    agg_kernel<<<gAgg, 256, 0, stream>>>(svals, row_off, cnt_in, csr_src, dvin, bg2, hbuf, NN);

    gemm_out64<<<GT, 256, 0, stream>>>(hbuf, W_out, b_out, out, NN);
}

// Round 8
// 637.082 us; speedup vs baseline: 1.9708x; 1.0726x over previous
//
#include <hip/hip_runtime.h>

#define NN   100000
#define EE   1600000
#define HIDF 128
#define OUTF 64
#define KSEL 32
#define BSH  3                   // log2(nodes per bucket)
#define NBK  (NN >> BSH)         // 12500 buckets (100000 = 12500*8 exact)
#define CAPSH 8                  // log2(records per bucket capacity)
#define CAP  (1 << CAPSH)        // 256; Poisson(128) max over 12500 buckets ~ 177
#define GT   ((NN + 63) / 64)    // 1563 gemm row tiles
#define GE   ((EE + 255) / 256)  // 6250 edge blocks

static __device__ __forceinline__ unsigned int sortable_key(float f) {
    unsigned int u = __float_as_uint(f);
    return (u & 0x80000000u) ? ~u : (u | 0x80000000u);
}

// ================= fused K1: edge binning (atomic-bound) + input GEMM (VALU-bound) =================
// R7 post-mortem: in-order block dispatch serialized the two streams (all 6250
// bin blocks dispatched before the first gemm tile; 211us ~= 150 bin + 60 gemm
// tail, VALUBusy 15% vs 43% standalone). v8: INTERLEAVE block types in index
// space -- every 5th block is a gemm tile (4:1 matches 6250:1563), so each CU
// holds ~3 bin + 1 gemm block from t=0 and gemm executes under atomic latency.
__global__ __launch_bounds__(256, 2) void fused_bin_relu(const int* __restrict__ src,
                                                         const int* __restrict__ dst,
                                                         int* __restrict__ bcnt,
                                                         int* __restrict__ scnt,
                                                         int* __restrict__ bin,
                                                         const float* __restrict__ X,
                                                         const float* __restrict__ W,
                                                         const float* __restrict__ bias,
                                                         float* __restrict__ out) {
    __shared__ float As[64][128];   // 32KB (gemm branch only)
    __shared__ float Ws[16][128];   // 8KB
    const int tid = threadIdx.x;
    const int g = blockIdx.x / 5;
    const int r = blockIdx.x % 5;

    if (r < 4) {
        // ---- bin branch (edge block g*4+r) ----
        int i = (g * 4 + r) * 256 + tid;
        if (i < EE) {
            int s = src[i];
            int d = dst[i];
            int b = d >> BSH;
            int pos = atomicAdd(&bcnt[b], 1);
            if (pos < CAP) bin[(b << CAPSH) + pos] = (s << BSH) | (d & ((1 << BSH) - 1));
            atomicAdd(&scnt[s], 1);
        }
        return;
    }

    // ---- gemm_relu branch (verified R3 body; 40KB LDS, reg-dbuf W chunks) ----
    const int rbase = g * 64;
    const int cc = tid & 31;
    const int r0 = (tid >> 5) * 8;
    const int n = NN;
    float acc[8][4];
#pragma unroll
    for (int i = 0; i < 8; ++i) { acc[i][0] = 0.f; acc[i][1] = 0.f; acc[i][2] = 0.f; acc[i][3] = 0.f; }

    float4 wreg0 = *(const float4*)(W + (size_t)tid * 4);
    float4 wreg1 = *(const float4*)(W + (size_t)(tid + 256) * 4);

    // stage A (row-guarded: x is not padded)
#pragma unroll
    for (int q = 0; q < 8; ++q) {
        int f = q * 256 + tid;
        int row = rbase + (f >> 5);
        float4 v = make_float4(0.f, 0.f, 0.f, 0.f);
        if (row < n) v = *(const float4*)(X + (size_t)row * 128 + (f & 31) * 4);
        *(float4*)&As[f >> 5][(f & 31) * 4] = v;
    }

    for (int p = 0; p < 8; ++p) {
        const int kb = p * 16;
        if (p) __syncthreads();
        *(float4*)&Ws[tid >> 5][(tid & 31) * 4] = wreg0;
        *(float4*)&Ws[(tid >> 5) + 8][(tid & 31) * 4] = wreg1;
        if (p < 7) {
            const float* wp = W + (size_t)(kb + 16) * 128;
            wreg0 = *(const float4*)(wp + (size_t)tid * 4);
            wreg1 = *(const float4*)(wp + (size_t)(tid + 256) * 4);
        }
        __syncthreads();
#pragma unroll
        for (int kq = 0; kq < 4; ++kq) {
            int k = kq * 4;
            float4 w0 = *(float4*)&Ws[k + 0][cc * 4];
            float4 w1 = *(float4*)&Ws[k + 1][cc * 4];
            float4 w2 = *(float4*)&Ws[k + 2][cc * 4];
            float4 w3 = *(float4*)&Ws[k + 3][cc * 4];
#pragma unroll
            for (int i = 0; i < 8; ++i) {
                float4 a = *(float4*)&As[r0 + i][kb + k];
                acc[i][0] += a.x * w0.x + a.y * w1.x + a.z * w2.x + a.w * w3.x;
                acc[i][1] += a.x * w0.y + a.y * w1.y + a.z * w2.y + a.w * w3.y;
                acc[i][2] += a.x * w0.z + a.y * w1.z + a.z * w2.z + a.w * w3.z;
                acc[i][3] += a.x * w0.w + a.y * w1.w + a.z * w2.w + a.w * w3.w;
            }
        }
    }
    float4 b4 = *(const float4*)(bias + cc * 4);
#pragma unroll
    for (int i = 0; i < 8; ++i) {
        int gr = rbase + r0 + i;
        if (gr < n) {
            float4 o = make_float4(fmaxf(acc[i][0] + b4.x, 0.f), fmaxf(acc[i][1] + b4.y, 0.f),
                                   fmaxf(acc[i][2] + b4.z, 0.f), fmaxf(acc[i][3] + b4.w, 0.f));
            *(float4*)(out + (size_t)gr * 128 + cc * 4) = o;
        }
    }
}

// ================= gemm_maxk body (shared by fused K2 and standalone layer-2) =================
// ds = rsqrtf(scnt[row]) inline (removes dvout_pass dependency).
static __device__ __forceinline__ void gemm_maxk_body(float (*As)[128], float (*Ws)[128],
                                                      const float* __restrict__ A,
                                                      const float* __restrict__ W,
                                                      const float* __restrict__ bias,
                                                      const int* __restrict__ scnt,
                                                      float* __restrict__ svals,
                                                      int n, int rbase) {
    const int tid = threadIdx.x;
    const int cc = tid & 31;
    const int r0 = (tid >> 5) * 8;
    float acc[8][4];
#pragma unroll
    for (int i = 0; i < 8; ++i) { acc[i][0] = 0.f; acc[i][1] = 0.f; acc[i][2] = 0.f; acc[i][3] = 0.f; }

    float4 wreg0 = *(const float4*)(W + (size_t)tid * 4);
    float4 wreg1 = *(const float4*)(W + (size_t)(tid + 256) * 4);

    // stage A (hbuf is row-padded: unguarded)
#pragma unroll
    for (int q = 0; q < 8; ++q) {
        int f = q * 256 + tid;
        *(float4*)&As[f >> 5][(f & 31) * 4] =
            *(const float4*)(A + (size_t)rbase * 128 + (size_t)f * 4);
    }

    for (int p = 0; p < 8; ++p) {
        const int kb = p * 16;
        if (p) __syncthreads();
        *(float4*)&Ws[tid >> 5][(tid & 31) * 4] = wreg0;
        *(float4*)&Ws[(tid >> 5) + 8][(tid & 31) * 4] = wreg1;
        if (p < 7) {
            const float* wp = W + (size_t)(kb + 16) * 128;
            wreg0 = *(const float4*)(wp + (size_t)tid * 4);
            wreg1 = *(const float4*)(wp + (size_t)(tid + 256) * 4);
        }
        __syncthreads();
#pragma unroll
        for (int kq = 0; kq < 4; ++kq) {
            int k = kq * 4;
            float4 w0 = *(float4*)&Ws[k + 0][cc * 4];
            float4 w1 = *(float4*)&Ws[k + 1][cc * 4];
            float4 w2 = *(float4*)&Ws[k + 2][cc * 4];
            float4 w3 = *(float4*)&Ws[k + 3][cc * 4];
#pragma unroll
            for (int i = 0; i < 8; ++i) {
                float4 a = *(float4*)&As[r0 + i][kb + k];
                acc[i][0] += a.x * w0.x + a.y * w1.x + a.z * w2.x + a.w * w3.x;
                acc[i][1] += a.x * w0.y + a.y * w1.y + a.z * w2.y + a.w * w3.y;
                acc[i][2] += a.x * w0.z + a.y * w1.z + a.z * w2.z + a.w * w3.z;
                acc[i][3] += a.x * w0.w + a.y * w1.w + a.z * w2.w + a.w * w3.w;
            }
        }
    }

    // ---- fused MaxK select (verified R0 logic) ----
    const int lane = tid & 63;
    const int wvi = tid >> 6;
    const bool up = lane >= 32;
    const unsigned lt32 = (1u << (lane & 31)) - 1u;
    float4 b4 = *(const float4*)(bias + cc * 4);

    unsigned keys[8][4];
#pragma unroll
    for (int i = 0; i < 8; ++i) {
        acc[i][0] += b4.x; acc[i][1] += b4.y; acc[i][2] += b4.z; acc[i][3] += b4.w;
        keys[i][0] = sortable_key(acc[i][0]);
        keys[i][1] = sortable_key(acc[i][1]);
        keys[i][2] = sortable_key(acc[i][2]);
        keys[i][3] = sortable_key(acc[i][3]);
    }
    unsigned prefL[8], prefU[8];
#pragma unroll
    for (int i = 0; i < 8; ++i) { prefL[i] = 0u; prefU[i] = 0u; }

    for (int bit = 31; bit >= 8; --bit) {
        unsigned msk = 1u << bit;
#pragma unroll
        for (int i = 0; i < 8; ++i) {
            unsigned cL = prefL[i] | msk;
            unsigned cU = prefU[i] | msk;
            unsigned myc = up ? cU : cL;
            unsigned long long b0 = __ballot(keys[i][0] >= myc);
            unsigned long long b1 = __ballot(keys[i][1] >= myc);
            unsigned long long b2 = __ballot(keys[i][2] >= myc);
            unsigned long long b3 = __ballot(keys[i][3] >= myc);
            int cntL = __popc((unsigned)b0) + __popc((unsigned)b1) +
                       __popc((unsigned)b2) + __popc((unsigned)b3);
            int cntU = __popc((unsigned)(b0 >> 32)) + __popc((unsigned)(b1 >> 32)) +
                       __popc((unsigned)(b2 >> 32)) + __popc((unsigned)(b3 >> 32));
            prefL[i] = (cntL >= KSEL) ? cL : prefL[i];
            prefU[i] = (cntU >= KSEL) ? cU : prefU[i];
        }
    }

#pragma unroll 1
    for (int i = 0; i < 8; ++i) {
        int row = rbase + 16 * wvi + i + (up ? 8 : 0);
        unsigned myp = up ? prefU[i] : prefL[i];
        unsigned kb0 = keys[i][0] & 0xFFFFFF00u, kb1 = keys[i][1] & 0xFFFFFF00u;
        unsigned kb2 = keys[i][2] & 0xFFFFFF00u, kb3 = keys[i][3] & 0xFFFFFF00u;
        unsigned long long g0 = __ballot(kb0 > myp), g1 = __ballot(kb1 > myp);
        unsigned long long g2 = __ballot(kb2 > myp), g3 = __ballot(kb3 > myp);
        unsigned long long e0 = __ballot(kb0 == myp), e1 = __ballot(kb1 == myp);
        unsigned long long e2 = __ballot(kb2 == myp), e3 = __ballot(kb3 == myp);
        unsigned gh0 = up ? (unsigned)(g0 >> 32) : (unsigned)g0;
        unsigned gh1 = up ? (unsigned)(g1 >> 32) : (unsigned)g1;
        unsigned gh2 = up ? (unsigned)(g2 >> 32) : (unsigned)g2;
        unsigned gh3 = up ? (unsigned)(g3 >> 32) : (unsigned)g3;
        unsigned eh0 = up ? (unsigned)(e0 >> 32) : (unsigned)e0;
        unsigned eh1 = up ? (unsigned)(e1 >> 32) : (unsigned)e1;
        unsigned eh2 = up ? (unsigned)(e2 >> 32) : (unsigned)e2;
        unsigned eh3 = up ? (unsigned)(e3 >> 32) : (unsigned)e3;
        int m = __popc(gh0) + __popc(gh1) + __popc(gh2) + __popc(gh3);
        int need = KSEL - m;
        int gpos = __popc(gh0 & lt32) + __popc(gh1 & lt32) + __popc(gh2 & lt32) + __popc(gh3 & lt32);
        int epos = __popc(eh0 & lt32) + __popc(eh1 & lt32) + __popc(eh2 & lt32) + __popc(eh3 & lt32);
        bool ok = row < n;
        float ds = 0.f;
        if (ok) ds = rsqrtf((float)max(scnt[row], 1));
        size_t base = (size_t)row * 32;
        unsigned cbit = (unsigned)(lane & 31);
        // j = 0
        {
            int slot = -1;
            if (kb0 > myp) slot = gpos;
            else if (kb0 == myp && epos < need) slot = m + epos;
            if (slot >= 0 && ok) {
                unsigned u = (__float_as_uint(acc[i][0] * ds) & 0xFFFFFF80u) | (unsigned)(cc * 4 + 0);
                svals[base + slot] = __uint_as_float(u);
            }
            gpos += (gh0 >> cbit) & 1u;
            epos += (eh0 >> cbit) & 1u;
        }
        // j = 1
        {
            int slot = -1;
            if (kb1 > myp) slot = gpos;
            else if (kb1 == myp && epos < need) slot = m + epos;
            if (slot >= 0 && ok) {
                unsigned u = (__float_as_uint(acc[i][1] * ds) & 0xFFFFFF80u) | (unsigned)(cc * 4 + 1);
                svals[base + slot] = __uint_as_float(u);
            }
            gpos += (gh1 >> cbit) & 1u;
            epos += (eh1 >> cbit) & 1u;
        }
        // j = 2
        {
            int slot = -1;
            if (kb2 > myp) slot = gpos;
            else if (kb2 == myp && epos < need) slot = m + epos;
            if (slot >= 0 && ok) {
                unsigned u = (__float_as_uint(acc[i][2] * ds) & 0xFFFFFF80u) | (unsigned)(cc * 4 + 2);
                svals[base + slot] = __uint_as_float(u);
            }
            gpos += (gh2 >> cbit) & 1u;
            epos += (eh2 >> cbit) & 1u;
        }
        // j = 3
        {
            int slot = -1;
            if (kb3 > myp) slot = gpos;
            else if (kb3 == myp && epos < need) slot = m + epos;
            if (slot >= 0 && ok) {
                unsigned u = (__float_as_uint(acc[i][3] * ds) & 0xFFFFFF80u) | (unsigned)(cc * 4 + 3);
                svals[base + slot] = __uint_as_float(u);
            }
        }
    }
}

// ================= fused K2: gemm_maxk#1 (long) + csr_from_bin (short, hidden under it) =================
__global__ __launch_bounds__(256, 2) void fused_csr_maxk(const int* __restrict__ bin,
                                                         const int* __restrict__ bcnt,
                                                         int* __restrict__ row_off,
                                                         int* __restrict__ cnt_in,
                                                         float* __restrict__ dvin,
                                                         int* __restrict__ csr,
                                                         const float* __restrict__ A,
                                                         const float* __restrict__ W,
                                                         const float* __restrict__ bias,
                                                         const int* __restrict__ scnt,
                                                         float* __restrict__ svals) {
    __shared__ float As[64][128];
    __shared__ float Ws[16][128];
    const int tid = threadIdx.x;

    if (blockIdx.x >= GT) {
        // ---- csr branch: per-bucket node counts, offsets, scatter ----
        int* cnt8 = (int*)&As[0][0];
        int* cur8 = cnt8 + (1 << BSH);
        const int b = blockIdx.x - GT;
        if (tid < (1 << BSH)) cnt8[tid] = 0;
        __syncthreads();
        const int m = min(bcnt[b], CAP);
        const int base = b << CAPSH;
        for (int e = tid; e < m; e += 256) {
            atomicAdd(&cnt8[bin[base + e] & ((1 << BSH) - 1)], 1);
        }
        __syncthreads();
        if (tid < (1 << BSH)) {
            int pre = 0;
#pragma unroll
            for (int q = 0; q < (1 << BSH); ++q) pre += (q < tid) ? cnt8[q] : 0;
            int node = (b << BSH) + tid;
            int start = base + pre;
            if (node < NN) {
                row_off[node] = start;
                cnt_in[node] = cnt8[tid];
                dvin[node] = rsqrtf((float)max(cnt8[tid], 1));
            }
            cur8[tid] = start;
        }
        __syncthreads();
        for (int e = tid; e < m; e += 256) {
            int r = bin[base + e];
            int pos = atomicAdd(&cur8[r & ((1 << BSH) - 1)], 1);
            csr[pos] = r >> BSH;
        }
        return;
    }

    gemm_maxk_body(As, Ws, A, W, bias, scnt, svals, NN, blockIdx.x * 64);
}

// ================= standalone gemm_maxk (layer 2) =================
__global__ __launch_bounds__(256, 2) void gemm_maxk(const float* __restrict__ A,
                                                    const float* __restrict__ W,
                                                    const float* __restrict__ bias,
                                                    const int* __restrict__ scnt,
                                                    float* __restrict__ svals, int n) {
    __shared__ float As[64][128];
    __shared__ float Ws[16][128];
    gemm_maxk_body(As, Ws, A, W, bias, scnt, svals, n, blockIdx.x * 64);
}

// ---------------- CSR aggregation: atomic-free (unchanged) ----------------
__global__ __launch_bounds__(256) void agg_kernel(const float* __restrict__ svals,
                                                  const int* __restrict__ row_off,
                                                  const int* __restrict__ cnt_in,
                                                  const int* __restrict__ csr_src,
                                                  const float* __restrict__ dvin,
                                                  const float* __restrict__ bg,
                                                  float* __restrict__ out, int n) {
    __shared__ float acc[4][2][128];  // [wave][slot][feature], wave-private
    const int wv = threadIdx.x >> 6;
    const int lane = threadIdx.x & 63;
    const int sub = lane >> 5;   // which edge slot
    const int j = lane & 31;     // entry within record
    const int node = blockIdx.x * 4 + wv;
    float* base0 = &acc[wv][0][0];
    base0[lane] = 0.f;
    base0[lane + 64] = 0.f;
    base0[lane + 128] = 0.f;
    base0[lane + 192] = 0.f;
    if (node < n) {
        int s0 = row_off[node], s1 = s0 + cnt_in[node];
        float* Ac = &acc[wv][sub][0];
        int e = s0 + sub;
        for (; e + 2 < s1; e += 4) {
            int sA = csr_src[e];
            int sB = csr_src[e + 2];
            float vA = svals[(size_t)sA * 32 + j];
            float vB = svals[(size_t)sB * 32 + j];
            int fA = (int)(__float_as_uint(vA) & 127u);
            Ac[fA] += vA;
            int fB = (int)(__float_as_uint(vB) & 127u);
            Ac[fB] += vB;
        }
        for (; e < s1; e += 2) {
            int sA = csr_src[e];
            float vA = svals[(size_t)sA * 32 + j];
            int fA = (int)(__float_as_uint(vA) & 127u);
            Ac[fA] += vA;
        }
    }
    if (node < n) {
        float dv = dvin[node];
        float r0 = acc[wv][0][lane] + acc[wv][1][lane];
        float r1 = acc[wv][0][lane + 64] + acc[wv][1][lane + 64];
        out[(size_t)node * 128 + lane] = r0 * dv + bg[lane];
        out[(size_t)node * 128 + lane + 64] = r1 * dv + bg[lane + 64];
    }
}

// ---------------- GEMM [n,128] x [128,64] + bias -> d_out (unchanged, verified R3) ----------------
__global__ __launch_bounds__(256, 2) void gemm_out64(const float* __restrict__ A,
                                                     const float* __restrict__ W,
                                                     const float* __restrict__ bias,
                                                     float* __restrict__ out, int n) {
    __shared__ float As[64][128];   // 32KB
    __shared__ float Ws[32][64];    // 8KB
    const int tid = threadIdx.x;
    const int rbase = blockIdx.x * 64;
    const int cc = tid & 15;
    const int r0 = (tid >> 4) * 4;
    float acc[4][4];
#pragma unroll
    for (int i = 0; i < 4; ++i) { acc[i][0] = 0.f; acc[i][1] = 0.f; acc[i][2] = 0.f; acc[i][3] = 0.f; }

    float4 wreg0 = *(const float4*)(W + (size_t)tid * 4);
    float4 wreg1 = *(const float4*)(W + (size_t)(tid + 256) * 4);

#pragma unroll
    for (int q = 0; q < 8; ++q) {
        int f = q * 256 + tid;
        *(float4*)&As[f >> 5][(f & 31) * 4] =
            *(const float4*)(A + (size_t)rbase * 128 + (size_t)f * 4);   // hbuf padded
    }

    for (int p = 0; p < 4; ++p) {
        const int kb = p * 32;
        if (p) __syncthreads();
        *(float4*)&Ws[tid >> 4][(tid & 15) * 4] = wreg0;
        *(float4*)&Ws[(tid >> 4) + 16][(tid & 15) * 4] = wreg1;
        if (p < 3) {
            const float* wp = W + (size_t)(kb + 32) * 64;
            wreg0 = *(const float4*)(wp + (size_t)tid * 4);
            wreg1 = *(const float4*)(wp + (size_t)(tid + 256) * 4);
        }
        __syncthreads();
#pragma unroll
        for (int kq = 0; kq < 8; ++kq) {
            int k = kq * 4;
            float4 w0 = *(float4*)&Ws[k + 0][cc * 4];
            float4 w1 = *(float4*)&Ws[k + 1][cc * 4];
            float4 w2 = *(float4*)&Ws[k + 2][cc * 4];
            float4 w3 = *(float4*)&Ws[k + 3][cc * 4];
#pragma unroll
            for (int i = 0; i < 4; ++i) {
                float4 a = *(float4*)&As[r0 + i][kb + k];
                acc[i][0] += a.x * w0.x + a.y * w1.x + a.z * w2.x + a.w * w3.x;
                acc[i][1] += a.x * w0.y + a.y * w1.y + a.z * w2.y + a.w * w3.y;
                acc[i][2] += a.x * w0.z + a.y * w1.z + a.z * w2.z + a.w * w3.z;
                acc[i][3] += a.x * w0.w + a.y * w1.w + a.z * w2.w + a.w * w3.w;
            }
        }
    }
    float4 b4 = *(const float4*)(bias + cc * 4);
#pragma unroll
    for (int i = 0; i < 4; ++i) {
        int gr = rbase + r0 + i;
        if (gr < n) {
            float4 o = make_float4(acc[i][0] + b4.x, acc[i][1] + b4.y,
                                   acc[i][2] + b4.z, acc[i][3] + b4.w);
            *(float4*)(out + (size_t)gr * 64 + cc * 4) = o;
        }
    }
}

extern "C" void kernel_launch(void* const* d_in, const int* in_sizes, int n_in,
                              void* d_out, int out_size, void* d_ws, size_t ws_size,
                              hipStream_t stream) {
    const float* x     = (const float*)d_in[0];
    const int*   src   = (const int*)d_in[1];
    const int*   dst   = (const int*)d_in[2];
    const float* W_in  = (const float*)d_in[3];
    const float* b_in  = (const float*)d_in[4];
    const float* W1    = (const float*)d_in[5];
    const float* b1    = (const float*)d_in[6];
    const float* bg1   = (const float*)d_in[7];
    const float* W2    = (const float*)d_in[8];
    const float* b2    = (const float*)d_in[9];
    const float* bg2   = (const float*)d_in[10];
    const float* W_out = (const float*)d_in[11];
    const float* b_out = (const float*)d_in[12];
    float* out = (float*)d_out;

    char* p = (char*)d_ws;
    auto carve = [&](size_t bytes) {
        char* r = p;
        p += (bytes + 255) & ~(size_t)255;
        return r;
    };
    int*   scnt    = (int*)carve((size_t)NN * 4);
    int*   bcnt    = (int*)carve((size_t)NBK * 4);
    float* dvin    = (float*)carve((size_t)NN * 4);
    int*   row_off = (int*)carve((size_t)NN * 4);
    int*   cnt_in  = (int*)carve((size_t)NN * 4);
    int*   bin     = (int*)carve((size_t)NBK * CAP * 4);     // 12.8MB packed records
    int*   csr_src = (int*)carve((size_t)NBK * CAP * 4);     // 12.8MB fixed-stride
    float* hbuf    = (float*)carve((size_t)(NN + 128) * HIDF * 4);  // padded rows
    float* svals   = (float*)carve((size_t)NN * KSEL * 4);

    const int gAgg = (NN + 3) / 4;       // 25000

    hipMemsetAsync(scnt, 0, (size_t)NN * 4, stream);
    hipMemsetAsync(bcnt, 0, (size_t)NBK * 4, stream);

    // K1: binning (atomic stream) interleaved 4:1 with input GEMM (VALU stream)
    fused_bin_relu<<<GT * 5, 256, 0, stream>>>(src, dst, bcnt, scnt, bin,
                                               x, W_in, b_in, hbuf);
    // K2: layer-1 GEMM+MaxK overlapped with CSR materialization
    fused_csr_maxk<<<GT + NBK, 256, 0, stream>>>(bin, bcnt, row_off, cnt_in, dvin, csr_src,
                                                 hbuf, W1, b1, scnt, svals);
    agg_kernel<<<gAgg, 256, 0, stream>>>(svals, row_off, cnt_in, csr_src, dvin, bg1, hbuf, NN);

    gemm_maxk<<<GT, 256, 0, stream>>>(hbuf, W2, b2, scnt, svals, NN);
    agg_kernel<<<gAgg, 256, 0, stream>>>(svals, row_off, cnt_in, csr_src, dvin, bg2, hbuf, NN);

    gemm_out64<<<GT, 256, 0, stream>>>(hbuf, W_out, b_out, out, NN);
}